// Round 3
// baseline (5665.713 us; speedup 1.0000x reference)
//
#include <hip/hip_runtime.h>
#include <hip/hip_bf16.h>

// Problem constants
#define B_  2
#define S_  2048
#define HID_ 2048
#define H_  16
#define HKV_ 4
#define D_  128

typedef __bf16 bf16_t;
typedef bf16_t bf16x8 __attribute__((ext_vector_type(8)));
typedef float f32x4 __attribute__((ext_vector_type(4)));

__device__ inline float bflo(unsigned u) { return __uint_as_float(u << 16); }
__device__ inline float bfhi(unsigned u) { return __uint_as_float(u & 0xffff0000u); }

// ---------------------------------------------------------------------------
// Runtime dtype detection: flag=1 if inputs are bf16, 0 if fp32.
// For bf16 N(0,1) data, u32 bits[14:7] is the low element's exponent field
// (~99% in [117,137]). For fp32 data those are uniform mantissa bits (~8%).
// ---------------------------------------------------------------------------
__global__ void detect_dtype(const unsigned* __restrict__ x, int* __restrict__ flag) {
    int lane = threadIdx.x;
    int c = 0;
#pragma unroll
    for (int i = 0; i < 16; ++i) {
        unsigned w = x[lane * 16 + i];
        unsigned e = (w >> 7) & 0xFF;
        c += (e >= 117 && e <= 137) ? 1 : 0;
    }
#pragma unroll
    for (int m = 1; m < 64; m <<= 1) c += __shfl_xor(c, m, 64);
    if (lane == 0) *flag = (c >= 512) ? 1 : 0;
}

// Load 8 contiguous elements as bf16x8 from either fp32 or bf16 storage.
template <bool F32>
__device__ __forceinline__ bf16x8 load8(const void* base, size_t off) {
    bf16x8 r;
    if constexpr (F32) {
        const float4* p = (const float4*)((const float*)base + off);
        float4 u = p[0], v = p[1];
        r[0] = (bf16_t)u.x; r[1] = (bf16_t)u.y; r[2] = (bf16_t)u.z; r[3] = (bf16_t)u.w;
        r[4] = (bf16_t)v.x; r[5] = (bf16_t)v.y; r[6] = (bf16_t)v.z; r[7] = (bf16_t)v.w;
    } else {
        r = *(const bf16x8*)((const bf16_t*)base + off);
    }
    return r;
}

// ---------------------------------------------------------------------------
// GEMM: C[m,n] = sum_k A[m,k] * W[n,k]. Direct-from-global MFMA 16x16x32 bf16.
// Block = 4 waves; 64x64 C tile. Fragment layout (learn_hip m89):
//   A: lane holds A[m=lane&15][k=(lane>>4)*8+j]  (16B contiguous)
//   B: lane holds W[n=lane&15][k=(lane>>4)*8+j]
//   C/D: row=(lane>>4)*4+reg, col=lane&15
// ---------------------------------------------------------------------------
template <bool AF32, bool WF32, bool OF32>
__device__ __forceinline__ void gemm_body(const void* __restrict__ A, const void* __restrict__ W,
                                          void* __restrict__ C, int M, int N, int K) {
    const int wave = threadIdx.x >> 6;
    const int lane = threadIdx.x & 63;
    const int r = lane & 15;
    const int quad = lane >> 4;
    const int m0 = blockIdx.y * 64 + wave * 16;
    const int n0 = blockIdx.x * 64;

    f32x4 acc[4] = {};
    const size_t aoff = (size_t)(m0 + r) * K + quad * 8;
    const size_t woff = (size_t)(n0 + r) * K + quad * 8;

    for (int k0 = 0; k0 < K; k0 += 32) {
        bf16x8 a = load8<AF32>(A, aoff + k0);
#pragma unroll
        for (int ns = 0; ns < 4; ++ns) {
            bf16x8 b = load8<WF32>(W, woff + (size_t)(ns * 16) * K + k0);
            acc[ns] = __builtin_amdgcn_mfma_f32_16x16x32_bf16(a, b, acc[ns], 0, 0, 0);
        }
    }

#pragma unroll
    for (int ns = 0; ns < 4; ++ns) {
#pragma unroll
        for (int reg = 0; reg < 4; ++reg) {
            int m = m0 + quad * 4 + reg;
            int n = n0 + ns * 16 + r;
            if constexpr (OF32) ((float*)C)[(size_t)m * N + n] = acc[ns][reg];
            else ((__hip_bfloat16*)C)[(size_t)m * N + n] = __float2bfloat16(acc[ns][reg]);
        }
    }
}

// mode 0: QKV projection (A,W in flag dtype; out bf16)
// mode 1: final projection (A bf16 always; W in flag dtype; out in flag dtype)
__global__ __launch_bounds__(256) void gemm_bt(const void* __restrict__ A, const void* __restrict__ W,
                                               void* __restrict__ C, int M, int N, int K,
                                               const int* __restrict__ flagp, int mode) {
    const int bf = *flagp;
    if (bf) {
        gemm_body<false, false, false>(A, W, C, M, N, K);
    } else if (mode == 0) {
        gemm_body<true, true, false>(A, W, C, M, N, K);
    } else {
        gemm_body<false, true, true>(A, W, C, M, N, K);
    }
}

// ---------------------------------------------------------------------------
// In-place RoPE + RMSNorm on bf16 buffer of layout [B*S, NH*D].
// One wave per (bs,h) row; lane d handles pair (d, d+64).
// ---------------------------------------------------------------------------
__global__ __launch_bounds__(256) void rope_rms(__hip_bfloat16* __restrict__ qk,
                                                const void* __restrict__ cosp,
                                                const void* __restrict__ sinp,
                                                int NH, const int* __restrict__ flagp) {
    const int bf = *flagp;
    const int wave = threadIdx.x >> 6;
    const int lane = threadIdx.x & 63;
    const int row = blockIdx.x * 4 + wave;   // row = bs*NH + h
    const int bs = row / NH;
    const int s = bs % S_;

    __hip_bfloat16* p = qk + (size_t)row * D_;
    float x1 = __bfloat162float(p[lane]);
    float x2 = __bfloat162float(p[lane + 64]);
    float c, sn, eps;
    if (bf) {
        c   = __bfloat162float(((const __hip_bfloat16*)cosp)[s * 64 + lane]);
        sn  = __bfloat162float(((const __hip_bfloat16*)sinp)[s * 64 + lane]);
        eps = 0.0078125f;                     // finfo(bfloat16).eps
    } else {
        c   = ((const float*)cosp)[s * 64 + lane];
        sn  = ((const float*)sinp)[s * 64 + lane];
        eps = 1.1920929e-07f;                 // finfo(float32).eps
    }
    float y1 = x1 * c + x2 * sn;
    float y2 = x2 * c - x1 * sn;
    float ss = y1 * y1 + y2 * y2;
#pragma unroll
    for (int m = 1; m < 64; m <<= 1) ss += __shfl_xor(ss, m, 64);
    float rinv = rsqrtf(ss * (1.0f / 128.0f) + eps);
    p[lane]      = __float2bfloat16(y1 * rinv);
    p[lane + 64] = __float2bfloat16(y2 * rinv);
}

// ---------------------------------------------------------------------------
// Causal attention, one block (256 threads) per query row.
// Q: [B*S, H*D] bf16 ; K,V: [B*S, HKV*D] bf16 ; O aliases Q (safe: block
// reads only its own Q row into LDS before the final write).
// ---------------------------------------------------------------------------
__global__ __launch_bounds__(256) void attn(const __hip_bfloat16* __restrict__ Q,
                                            const __hip_bfloat16* __restrict__ K,
                                            const __hip_bfloat16* __restrict__ V,
                                            __hip_bfloat16* __restrict__ O) {
    __shared__ float qs[D_];
    __shared__ float sc[S_];
    __shared__ float red[4];
    __shared__ float po[4][D_];

    const int bid = blockIdx.x;           // (b*H + h)*S + qi
    const int qi = bid % S_;
    const int bh = bid / S_;
    const int h = bh % H_;
    const int b = bh / H_;
    const int kvh = h >> 2;               // H/HKV = 4
    const int tid = threadIdx.x;
    const int lane = tid & 63;

    const __hip_bfloat16* qptr = Q + ((size_t)(b * S_ + qi) * H_ + h) * D_;
    if (tid < D_) qs[tid] = __bfloat162float(qptr[tid]) * 0.08838834764831845f; // D^-0.5
    __syncthreads();

    const int nk = qi + 1;
    const size_t kvstride = HKV_ * D_;
    const __hip_bfloat16* Kb = K + (size_t)b * S_ * kvstride + kvh * D_;
    const __hip_bfloat16* Vb = V + (size_t)b * S_ * kvstride + kvh * D_;

    // ---- scores ----
    float lmax = -1e30f;
    for (int k = tid; k < nk; k += 256) {
        const uint4* kr = (const uint4*)(Kb + (size_t)k * kvstride);
        float acc = 0.f;
#pragma unroll
        for (int c = 0; c < 16; ++c) {
            uint4 u = kr[c];
            int d = c * 8;
            acc += bflo(u.x) * qs[d]     + bfhi(u.x) * qs[d + 1]
                 + bflo(u.y) * qs[d + 2] + bfhi(u.y) * qs[d + 3]
                 + bflo(u.z) * qs[d + 4] + bfhi(u.z) * qs[d + 5]
                 + bflo(u.w) * qs[d + 6] + bfhi(u.w) * qs[d + 7];
        }
        sc[k] = acc;
        lmax = fmaxf(lmax, acc);
    }
#pragma unroll
    for (int m = 1; m < 64; m <<= 1) lmax = fmaxf(lmax, __shfl_xor(lmax, m, 64));
    if (lane == 0) red[tid >> 6] = lmax;
    __syncthreads();
    const float gmax = fmaxf(fmaxf(red[0], red[1]), fmaxf(red[2], red[3]));
    __syncthreads();

    // ---- exp + sum ----
    float lsum = 0.f;
    for (int k = tid; k < nk; k += 256) {
        float p = __expf(sc[k] - gmax);
        sc[k] = p;
        lsum += p;
    }
#pragma unroll
    for (int m = 1; m < 64; m <<= 1) lsum += __shfl_xor(lsum, m, 64);
    if (lane == 0) red[tid >> 6] = lsum;
    __syncthreads();
    const float inv = 1.0f / (red[0] + red[1] + red[2] + red[3]);

    // ---- PV ----
    const int part = tid >> 6;            // 4-way key split
    const int d0 = (tid & 63) * 2;
    float o0 = 0.f, o1 = 0.f;
    for (int k = part; k < nk; k += 4) {
        float p = sc[k];
        unsigned u = *(const unsigned*)(Vb + (size_t)k * kvstride + d0);
        o0 += p * bflo(u);
        o1 += p * bfhi(u);
    }
    po[part][d0] = o0;
    po[part][d0 + 1] = o1;
    __syncthreads();
    if (tid < D_) {
        float o = (po[0][tid] + po[1][tid] + po[2][tid] + po[3][tid]) * inv;
        O[((size_t)(b * S_ + qi) * H_ + h) * D_ + tid] = __float2bfloat16(o);
    }
}

// ---------------------------------------------------------------------------
extern "C" void kernel_launch(void* const* d_in, const int* in_sizes, int n_in,
                              void* d_out, int out_size, void* d_ws, size_t ws_size,
                              hipStream_t stream) {
    const void* x    = d_in[0];
    const void* cosp = d_in[1];
    const void* sinp = d_in[2];
    const void* Wq   = d_in[3];
    const void* Wk   = d_in[4];
    const void* Wv   = d_in[5];
    const void* Wo   = d_in[6];

    const int M = B_ * S_;                 // 4096

    // Memory plan:
    //   qb   [M, H*D]   bf16 = 16 MB -> d_ws      (attention output in-place)
    //   flag int              -> d_ws + 16 MB
    //   kb   [M, HKV*D] bf16 = 4 MB  -> d_out[0:] (dead before final GEMM)
    //   vb   [M, HKV*D] bf16 = 4 MB  -> d_out[4MB:]
    __hip_bfloat16* qb = (__hip_bfloat16*)d_ws;
    int* flag = (int*)((char*)d_ws + (size_t)M * (H_ * D_) * sizeof(__hip_bfloat16));
    __hip_bfloat16* kb = (__hip_bfloat16*)d_out;
    __hip_bfloat16* vb = kb + (size_t)M * (HKV_ * D_);

    detect_dtype<<<1, 64, 0, stream>>>((const unsigned*)x, flag);

    // QKV projections (out bf16)
    gemm_bt<<<dim3((H_ * D_) / 64, M / 64), 256, 0, stream>>>(x, Wq, qb, M, H_ * D_, HID_, flag, 0);
    gemm_bt<<<dim3((HKV_ * D_) / 64, M / 64), 256, 0, stream>>>(x, Wk, kb, M, HKV_ * D_, HID_, flag, 0);
    gemm_bt<<<dim3((HKV_ * D_) / 64, M / 64), 256, 0, stream>>>(x, Wv, vb, M, HKV_ * D_, HID_, flag, 0);

    // RoPE + RMSNorm in-place on q and k
    rope_rms<<<(B_ * S_ * H_) / 4, 256, 0, stream>>>(qb, cosp, sinp, H_, flag);
    rope_rms<<<(B_ * S_ * HKV_) / 4, 256, 0, stream>>>(kb, cosp, sinp, HKV_, flag);

    // Attention (output written in-place over qb)
    attn<<<B_ * H_ * S_, 256, 0, stream>>>(qb, kb, vb, qb);

    // Output projection (overwrites d_out; kb/vb dead). A=qb is bf16; W/out per flag.
    gemm_bt<<<dim3(HID_ / 64, M / 64), 256, 0, stream>>>(qb, Wo, d_out, M, HID_, H_ * D_, flag, 1);
}

// Round 4
// 1777.420 us; speedup vs baseline: 3.1876x; 3.1876x over previous
//
#include <hip/hip_runtime.h>
#include <hip/hip_bf16.h>

// Problem constants
#define B_  2
#define S_  2048
#define HID_ 2048
#define H_  16
#define HKV_ 4
#define D_  128

typedef __bf16 bf16_t;
typedef bf16_t bf16x8 __attribute__((ext_vector_type(8)));
typedef float f32x4 __attribute__((ext_vector_type(4)));

__device__ inline float bflo(unsigned u) { return __uint_as_float(u << 16); }
__device__ inline float bfhi(unsigned u) { return __uint_as_float(u & 0xffff0000u); }

// ---------------------------------------------------------------------------
// Runtime dtype detection: flag=1 if inputs are bf16, 0 if fp32.
// ---------------------------------------------------------------------------
__global__ void detect_dtype(const unsigned* __restrict__ x, int* __restrict__ flag) {
    int lane = threadIdx.x;
    int c = 0;
#pragma unroll
    for (int i = 0; i < 16; ++i) {
        unsigned w = x[lane * 16 + i];
        unsigned e = (w >> 7) & 0xFF;
        c += (e >= 117 && e <= 137) ? 1 : 0;
    }
#pragma unroll
    for (int m = 1; m < 64; m <<= 1) c += __shfl_xor(c, m, 64);
    if (lane == 0) *flag = (c >= 512) ? 1 : 0;
}

// Load 8 contiguous elements as bf16x8 from either fp32 or bf16 storage.
template <bool F32>
__device__ __forceinline__ bf16x8 load8(const void* base, size_t off) {
    bf16x8 r;
    if constexpr (F32) {
        const float4* p = (const float4*)((const float*)base + off);
        float4 u = p[0], v = p[1];
        r[0] = (bf16_t)u.x; r[1] = (bf16_t)u.y; r[2] = (bf16_t)u.z; r[3] = (bf16_t)u.w;
        r[4] = (bf16_t)v.x; r[5] = (bf16_t)v.y; r[6] = (bf16_t)v.z; r[7] = (bf16_t)v.w;
    } else {
        r = *(const bf16x8*)((const bf16_t*)base + off);
    }
    return r;
}

// ---------------------------------------------------------------------------
// GEMM: C[m,n] = sum_k A[m,k] * W[n,k]. Direct-from-global MFMA 16x16x32 bf16.
// ---------------------------------------------------------------------------
template <bool AF32, bool WF32, bool OF32>
__device__ __forceinline__ void gemm_body(const void* __restrict__ A, const void* __restrict__ W,
                                          void* __restrict__ C, int M, int N, int K) {
    const int wave = threadIdx.x >> 6;
    const int lane = threadIdx.x & 63;
    const int r = lane & 15;
    const int quad = lane >> 4;
    const int m0 = blockIdx.y * 64 + wave * 16;
    const int n0 = blockIdx.x * 64;

    f32x4 acc[4] = {};
    const size_t aoff = (size_t)(m0 + r) * K + quad * 8;
    const size_t woff = (size_t)(n0 + r) * K + quad * 8;

    for (int k0 = 0; k0 < K; k0 += 32) {
        bf16x8 a = load8<AF32>(A, aoff + k0);
#pragma unroll
        for (int ns = 0; ns < 4; ++ns) {
            bf16x8 b = load8<WF32>(W, woff + (size_t)(ns * 16) * K + k0);
            acc[ns] = __builtin_amdgcn_mfma_f32_16x16x32_bf16(a, b, acc[ns], 0, 0, 0);
        }
    }

#pragma unroll
    for (int ns = 0; ns < 4; ++ns) {
#pragma unroll
        for (int reg = 0; reg < 4; ++reg) {
            int m = m0 + quad * 4 + reg;
            int n = n0 + ns * 16 + r;
            if constexpr (OF32) ((float*)C)[(size_t)m * N + n] = acc[ns][reg];
            else ((__hip_bfloat16*)C)[(size_t)m * N + n] = __float2bfloat16(acc[ns][reg]);
        }
    }
}

__global__ __launch_bounds__(256) void gemm_bt(const void* __restrict__ A, const void* __restrict__ W,
                                               void* __restrict__ C, int M, int N, int K,
                                               const int* __restrict__ flagp, int mode) {
    const int bf = *flagp;
    if (bf) {
        gemm_body<false, false, false>(A, W, C, M, N, K);
    } else if (mode == 0) {
        gemm_body<true, true, false>(A, W, C, M, N, K);
    } else {
        gemm_body<false, true, true>(A, W, C, M, N, K);
    }
}

// ---------------------------------------------------------------------------
// In-place RoPE + RMSNorm on bf16 buffer of layout [B*S, NH*D].
// ---------------------------------------------------------------------------
__global__ __launch_bounds__(256) void rope_rms(__hip_bfloat16* __restrict__ qk,
                                                const void* __restrict__ cosp,
                                                const void* __restrict__ sinp,
                                                int NH, const int* __restrict__ flagp) {
    const int bf = *flagp;
    const int wave = threadIdx.x >> 6;
    const int lane = threadIdx.x & 63;
    const int row = blockIdx.x * 4 + wave;   // row = bs*NH + h
    const int bs = row / NH;
    const int s = bs % S_;

    __hip_bfloat16* p = qk + (size_t)row * D_;
    float x1 = __bfloat162float(p[lane]);
    float x2 = __bfloat162float(p[lane + 64]);
    float c, sn, eps;
    if (bf) {
        c   = __bfloat162float(((const __hip_bfloat16*)cosp)[s * 64 + lane]);
        sn  = __bfloat162float(((const __hip_bfloat16*)sinp)[s * 64 + lane]);
        eps = 0.0078125f;
    } else {
        c   = ((const float*)cosp)[s * 64 + lane];
        sn  = ((const float*)sinp)[s * 64 + lane];
        eps = 1.1920929e-07f;
    }
    float y1 = x1 * c + x2 * sn;
    float y2 = x2 * c - x1 * sn;
    float ss = y1 * y1 + y2 * y2;
#pragma unroll
    for (int m = 1; m < 64; m <<= 1) ss += __shfl_xor(ss, m, 64);
    float rinv = rsqrtf(ss * (1.0f / 128.0f) + eps);
    p[lane]      = __float2bfloat16(y1 * rinv);
    p[lane + 64] = __float2bfloat16(y2 * rinv);
}

// ---------------------------------------------------------------------------
// Flash attention (MFMA). Block = 4 waves; 64 q-rows of one (b,h).
// Wave owns 16 q-rows (Q frags in registers). K-loop over 32-key tiles:
//   Ks[32][136]  : K tile as-is, padded rows (2-way-free b128 frag reads)
//   Vt[128][32]  : V tile transposed, key-blocks XOR-swizzled by
//                  s(d)=((d>>1)&3)^((d>>3)&3)  (b128 reads, <=4-way writes)
//   Pb[w][16][40]: per-wave P round-trip, C-layout -> A-layout (m120)
// Online softmax in C-layout registers; row reductions = shfl_xor over the
// 16-lane quad group. O accumulates in 8 f32x4 frags; final /l and store.
// O aliases Q safely: block reads only its own (rows x head-cols) region
// into registers at start and writes exactly that region at the end.
// ---------------------------------------------------------------------------
#define KT_ 32
#define LDK 136
#define LDP 40

__global__ __launch_bounds__(256) void attn_flash(const __hip_bfloat16* __restrict__ Q,
                                                  const __hip_bfloat16* __restrict__ K,
                                                  const __hip_bfloat16* __restrict__ V,
                                                  __hip_bfloat16* __restrict__ O) {
    __shared__ unsigned short Ks[KT_][LDK];        // 8704 B
    __shared__ unsigned short Vt[D_ * KT_];        // 8192 B
    __shared__ __hip_bfloat16 Pb[4][16][LDP];      // 5120 B

    const int tid = threadIdx.x;
    const int w = tid >> 6;
    const int lane = tid & 63;
    const int r = lane & 15;
    const int quad = lane >> 4;

    const int qt = gridDim.x - 1 - blockIdx.x;     // big-work tiles dispatch first
    const int q0 = qt * 64;
    const int bh = blockIdx.y;
    const int h = bh % H_;
    const int b = bh / H_;
    const int kvh = h >> 2;

    // Q fragments (16 rows x 128 dims, 4 k-chunks), scaled later in fp32
    const int qw_lo = q0 + w * 16;
    const int qw_hi = qw_lo + 15;
    const bf16_t* qptr = (const bf16_t*)Q + ((size_t)(b * S_ + qw_lo + r)) * (H_ * D_) + h * D_ + quad * 8;
    bf16x8 qf[4];
#pragma unroll
    for (int c = 0; c < 4; ++c) qf[c] = *(const bf16x8*)(qptr + c * 32);

    f32x4 oacc[8] = {};
    float m_i[4], l_i[4];
#pragma unroll
    for (int g = 0; g < 4; ++g) { m_i[g] = -3e38f; l_i[g] = 0.f; }

    const size_t kvrow = HKV_ * D_;                // 512
    const bf16_t* Kg = (const bf16_t*)K + (size_t)b * S_ * kvrow + kvh * D_;
    const bf16_t* Vg = (const bf16_t*)V + (size_t)b * S_ * kvrow + kvh * D_;

    const int ntiles = q0 / KT_ + 2;
    const float scale = 0.08838834764831845f;      // D^-0.5

    for (int kt = 0; kt < ntiles; ++kt) {
        const int k0 = kt * KT_;
        __syncthreads();
        // ---- stage K and V tiles (2 uint4 chunks per thread each) ----
#pragma unroll
        for (int i = 0; i < 2; ++i) {
            const int c = tid + i * 256;
            const int key = c >> 4;                // 0..31
            const int dc = c & 15;                 // dim chunk of 8
            const size_t goff = (size_t)(k0 + key) * kvrow + dc * 8;
            *(uint4*)&Ks[key][dc * 8] = *(const uint4*)(Kg + goff);
            union { uint4 u; unsigned short s[8]; } vv;
            vv.u = *(const uint4*)(Vg + goff);
            const int sw = dc & 3;
#pragma unroll
            for (int j = 0; j < 8; ++j) {
                const int d = dc * 8 + j;
                const int cb = (key >> 3) ^ ((j >> 1) & 3) ^ sw;
                Vt[d * KT_ + cb * 8 + (key & 7)] = vv.s[j];
            }
        }
        __syncthreads();
        if (k0 > qw_hi) continue;                  // fully masked for this wave

        // ---- QK^T: S[16 x 32] ----
        f32x4 s0 = {}, s1 = {};
#pragma unroll
        for (int c = 0; c < 4; ++c) {
            bf16x8 kb0 = *(const bf16x8*)&Ks[r][c * 32 + quad * 8];
            bf16x8 kb1 = *(const bf16x8*)&Ks[16 + r][c * 32 + quad * 8];
            s0 = __builtin_amdgcn_mfma_f32_16x16x32_bf16(qf[c], kb0, s0, 0, 0, 0);
            s1 = __builtin_amdgcn_mfma_f32_16x16x32_bf16(qf[c], kb1, s1, 0, 0, 0);
        }

        // ---- scale + causal mask ----
        const bool bnd = (k0 + KT_ - 1) > qw_lo;
        float mt[4];
#pragma unroll
        for (int g = 0; g < 4; ++g) {
            s0[g] *= scale;
            s1[g] *= scale;
            if (bnd) {
                const int qrow = qw_lo + quad * 4 + g;
                if (k0 + r > qrow)      s0[g] = -3e38f;
                if (k0 + 16 + r > qrow) s1[g] = -3e38f;
            }
            mt[g] = fmaxf(s0[g], s1[g]);
        }
        // ---- row max across 16 lanes ----
#pragma unroll
        for (int msk = 1; msk < 16; msk <<= 1) {
#pragma unroll
            for (int g = 0; g < 4; ++g) mt[g] = fmaxf(mt[g], __shfl_xor(mt[g], msk, 64));
        }
        // ---- online softmax update ----
        float al[4], rs[4];
#pragma unroll
        for (int g = 0; g < 4; ++g) {
            const float mn = fmaxf(m_i[g], mt[g]);
            al[g] = __expf(m_i[g] - mn);
            m_i[g] = mn;
            const float p0 = __expf(s0[g] - mn);
            const float p1 = __expf(s1[g] - mn);
            s0[g] = p0;
            s1[g] = p1;
            rs[g] = p0 + p1;
#pragma unroll
            for (int ns = 0; ns < 8; ++ns) oacc[ns][g] *= al[g];
        }
#pragma unroll
        for (int msk = 1; msk < 16; msk <<= 1) {
#pragma unroll
            for (int g = 0; g < 4; ++g) rs[g] += __shfl_xor(rs[g], msk, 64);
        }
#pragma unroll
        for (int g = 0; g < 4; ++g) l_i[g] = l_i[g] * al[g] + rs[g];

        // ---- P: C-layout -> LDS -> A-layout ----
#pragma unroll
        for (int g = 0; g < 4; ++g) {
            const int row = quad * 4 + g;
            Pb[w][row][r]      = __float2bfloat16(s0[g]);
            Pb[w][row][16 + r] = __float2bfloat16(s1[g]);
        }
        bf16x8 pf = *(const bf16x8*)&Pb[w][r][quad * 8];

        // ---- PV: O += P[16x32] * V[32x128] ----
#pragma unroll
        for (int ns = 0; ns < 8; ++ns) {
            const int d = ns * 16 + r;
            const int cb = quad ^ ((r >> 1) & 3) ^ ((2 * ns + (r >> 3)) & 3);
            bf16x8 vf = *(const bf16x8*)&Vt[d * KT_ + cb * 8];
            oacc[ns] = __builtin_amdgcn_mfma_f32_16x16x32_bf16(pf, vf, oacc[ns], 0, 0, 0);
        }
    }

    // ---- epilogue: O / l, store ----
#pragma unroll
    for (int g = 0; g < 4; ++g) {
        const float inv = 1.0f / l_i[g];
        const int qrow = qw_lo + quad * 4 + g;
        __hip_bfloat16* op = O + ((size_t)(b * S_ + qrow)) * (H_ * D_) + h * D_;
#pragma unroll
        for (int ns = 0; ns < 8; ++ns)
            op[ns * 16 + r] = __float2bfloat16(oacc[ns][g] * inv);
    }
}

// ---------------------------------------------------------------------------
extern "C" void kernel_launch(void* const* d_in, const int* in_sizes, int n_in,
                              void* d_out, int out_size, void* d_ws, size_t ws_size,
                              hipStream_t stream) {
    const void* x    = d_in[0];
    const void* cosp = d_in[1];
    const void* sinp = d_in[2];
    const void* Wq   = d_in[3];
    const void* Wk   = d_in[4];
    const void* Wv   = d_in[5];
    const void* Wo   = d_in[6];

    const int M = B_ * S_;                 // 4096

    // Memory plan:
    //   qb   [M, H*D]   bf16 = 16 MB -> d_ws      (attention output in-place)
    //   flag int              -> d_ws + 16 MB
    //   kb   [M, HKV*D] bf16 = 4 MB  -> d_out[0:] (dead before final GEMM)
    //   vb   [M, HKV*D] bf16 = 4 MB  -> d_out[4MB:]
    __hip_bfloat16* qb = (__hip_bfloat16*)d_ws;
    int* flag = (int*)((char*)d_ws + (size_t)M * (H_ * D_) * sizeof(__hip_bfloat16));
    __hip_bfloat16* kb = (__hip_bfloat16*)d_out;
    __hip_bfloat16* vb = kb + (size_t)M * (HKV_ * D_);

    detect_dtype<<<1, 64, 0, stream>>>((const unsigned*)x, flag);

    // QKV projections (out bf16)
    gemm_bt<<<dim3((H_ * D_) / 64, M / 64), 256, 0, stream>>>(x, Wq, qb, M, H_ * D_, HID_, flag, 0);
    gemm_bt<<<dim3((HKV_ * D_) / 64, M / 64), 256, 0, stream>>>(x, Wk, kb, M, HKV_ * D_, HID_, flag, 0);
    gemm_bt<<<dim3((HKV_ * D_) / 64, M / 64), 256, 0, stream>>>(x, Wv, vb, M, HKV_ * D_, HID_, flag, 0);

    // RoPE + RMSNorm in-place on q and k
    rope_rms<<<(B_ * S_ * H_) / 4, 256, 0, stream>>>(qb, cosp, sinp, H_, flag);
    rope_rms<<<(B_ * S_ * HKV_) / 4, 256, 0, stream>>>(kb, cosp, sinp, HKV_, flag);

    // Flash attention (output written in-place over qb)
    attn_flash<<<dim3(S_ / 64, B_ * H_), 256, 0, stream>>>(qb, kb, vb, qb);

    // Output projection (overwrites d_out; kb/vb dead)
    gemm_bt<<<dim3(HID_ / 64, M / 64), 256, 0, stream>>>(qb, Wo, d_out, M, HID_, H_ * D_, flag, 1);
}

// Round 5
// 526.407 us; speedup vs baseline: 10.7630x; 3.3765x over previous
//
#include <hip/hip_runtime.h>
#include <hip/hip_bf16.h>

// Problem constants
#define B_  2
#define S_  2048
#define HID_ 2048
#define H_  16
#define HKV_ 4
#define D_  128

typedef __bf16 bf16_t;
typedef bf16_t bf16x8 __attribute__((ext_vector_type(8)));
typedef float f32x4 __attribute__((ext_vector_type(4)));

typedef __attribute__((address_space(3))) unsigned int lds_u32_t;
typedef const __attribute__((address_space(1))) unsigned int glob_u32_t;

// async global->LDS, 16 B per lane; LDS dest = wave-uniform base + lane*16
__device__ __forceinline__ void gl2lds16(const bf16_t* g, bf16_t* l) {
    __builtin_amdgcn_global_load_lds((glob_u32_t*)g, (lds_u32_t*)l, 16, 0, 0);
}

__device__ inline float bflo(unsigned u) { return __uint_as_float(u << 16); }
__device__ inline float bfhi(unsigned u) { return __uint_as_float(u & 0xffff0000u); }

// ---------------------------------------------------------------------------
// Runtime dtype detection: flag=1 if inputs are bf16, 0 if fp32.
// ---------------------------------------------------------------------------
__global__ void detect_dtype(const unsigned* __restrict__ x, int* __restrict__ flag) {
    int lane = threadIdx.x;
    int c = 0;
#pragma unroll
    for (int i = 0; i < 16; ++i) {
        unsigned w = x[lane * 16 + i];
        unsigned e = (w >> 7) & 0xFF;
        c += (e >= 117 && e <= 137) ? 1 : 0;
    }
#pragma unroll
    for (int m = 1; m < 64; m <<= 1) c += __shfl_xor(c, m, 64);
    if (lane == 0) *flag = (c >= 512) ? 1 : 0;
}

// ---------------------------------------------------------------------------
// Conversion pass: src (fp32 or bf16 per flag) -> bf16 dst. 8 elems/thread.
// Up to 4 segments selected by blockIdx.y.
// ---------------------------------------------------------------------------
struct Cseg { const void* src; bf16_t* dst; int n8; };

__global__ __launch_bounds__(256) void convert_bf16(Cseg s0, Cseg s1, Cseg s2, Cseg s3,
                                                    const int* __restrict__ flagp) {
    Cseg s = (blockIdx.y == 0) ? s0 : (blockIdx.y == 1) ? s1 : (blockIdx.y == 2) ? s2 : s3;
    const int i = blockIdx.x * 256 + threadIdx.x;
    if (i >= s.n8) return;
    if (*flagp) {
        ((uint4*)s.dst)[i] = ((const uint4*)s.src)[i];
    } else {
        const float4* p = (const float4*)s.src + (size_t)i * 2;
        float4 u = p[0], v = p[1];
        bf16x8 r;
        r[0] = (bf16_t)u.x; r[1] = (bf16_t)u.y; r[2] = (bf16_t)u.z; r[3] = (bf16_t)u.w;
        r[4] = (bf16_t)v.x; r[5] = (bf16_t)v.y; r[6] = (bf16_t)v.z; r[7] = (bf16_t)v.w;
        *(bf16x8*)(s.dst + (size_t)i * 8) = r;
    }
}

// ---------------------------------------------------------------------------
// m97-structure GEMM: C[m,n] = sum_k A[m,k]*W[n,k], A/W bf16 row-major.
// 128x128 tile, BK=32, LDS staging via global_load_lds width=16.
// 4 waves; wave w owns 64x64 quadrant (mh=(w&1)*64, nh=(w>>1)*64) = 4x4
// subtiles of 16x16x32 MFMA. LDS unpadded [128][32] (required by the
// wave-uniform-base + lane*16 rule of global_load_lds).
// osel=1: output fp32 when *flagp==0 else bf16. osel=0: always bf16.
// ---------------------------------------------------------------------------
__global__ __launch_bounds__(256) void gemm_lds(const bf16_t* __restrict__ A,
                                                const bf16_t* __restrict__ W,
                                                void* __restrict__ C,
                                                int M, int N, int K,
                                                const int* __restrict__ flagp, int osel) {
    __shared__ bf16_t As[128 * 32];
    __shared__ bf16_t Bs[128 * 32];

    const int tid = threadIdx.x;
    const int w = tid >> 6;
    const int lane = tid & 63;
    const int r = lane & 15;
    const int quad = lane >> 4;
    const int m0 = blockIdx.y * 128;
    const int n0 = blockIdx.x * 128;
    const bool of32 = osel && (*flagp == 0);

    const int mh = (w & 1) * 64;
    const int nh = (w >> 1) * 64;

    // staging: wave w loads 16-row chunks c0 and c0+1 of both tiles.
    // lane covers row = chunk*16 + lane/4, cols (lane%4)*8 .. +8
    const int c0 = w * 2;
    const int srow = lane >> 2;
    const int scol = (lane & 3) * 8;
    const bf16_t* Ag0 = A + (size_t)(m0 + c0 * 16 + srow) * K + scol;
    const bf16_t* Ag1 = A + (size_t)(m0 + c0 * 16 + 16 + srow) * K + scol;
    const bf16_t* Wg0 = W + (size_t)(n0 + c0 * 16 + srow) * K + scol;
    const bf16_t* Wg1 = W + (size_t)(n0 + c0 * 16 + 16 + srow) * K + scol;
    bf16_t* Al0 = As + c0 * 512;          // wave-uniform LDS bases
    bf16_t* Al1 = As + (c0 + 1) * 512;
    bf16_t* Bl0 = Bs + c0 * 512;
    bf16_t* Bl1 = Bs + (c0 + 1) * 512;

    f32x4 acc[4][4] = {};

    for (int k0 = 0; k0 < K; k0 += 32) {
        __syncthreads();
        gl2lds16(Ag0 + k0, Al0);
        gl2lds16(Ag1 + k0, Al1);
        gl2lds16(Wg0 + k0, Bl0);
        gl2lds16(Wg1 + k0, Bl1);
        __syncthreads();

        bf16x8 a[4], b[4];
#pragma unroll
        for (int mi = 0; mi < 4; ++mi)
            a[mi] = *(const bf16x8*)&As[(mh + mi * 16 + r) * 32 + quad * 8];
#pragma unroll
        for (int ni = 0; ni < 4; ++ni)
            b[ni] = *(const bf16x8*)&Bs[(nh + ni * 16 + r) * 32 + quad * 8];
#pragma unroll
        for (int mi = 0; mi < 4; ++mi)
#pragma unroll
            for (int ni = 0; ni < 4; ++ni)
                acc[mi][ni] = __builtin_amdgcn_mfma_f32_16x16x32_bf16(a[mi], b[ni], acc[mi][ni], 0, 0, 0);
    }

#pragma unroll
    for (int mi = 0; mi < 4; ++mi) {
#pragma unroll
        for (int ni = 0; ni < 4; ++ni) {
#pragma unroll
            for (int g = 0; g < 4; ++g) {
                const int row = m0 + mh + mi * 16 + quad * 4 + g;
                const int col = n0 + nh + ni * 16 + r;
                if (of32) ((float*)C)[(size_t)row * N + col] = acc[mi][ni][g];
                else ((__hip_bfloat16*)C)[(size_t)row * N + col] = __float2bfloat16(acc[mi][ni][g]);
            }
        }
    }
}

// ---------------------------------------------------------------------------
// Fallback direct-from-global GEMM (round-4, correctness-proven).
// ---------------------------------------------------------------------------
template <bool F32>
__device__ __forceinline__ bf16x8 load8(const void* base, size_t off) {
    bf16x8 r;
    if constexpr (F32) {
        const float4* p = (const float4*)((const float*)base + off);
        float4 u = p[0], v = p[1];
        r[0] = (bf16_t)u.x; r[1] = (bf16_t)u.y; r[2] = (bf16_t)u.z; r[3] = (bf16_t)u.w;
        r[4] = (bf16_t)v.x; r[5] = (bf16_t)v.y; r[6] = (bf16_t)v.z; r[7] = (bf16_t)v.w;
    } else {
        r = *(const bf16x8*)((const bf16_t*)base + off);
    }
    return r;
}

template <bool AF32, bool WF32, bool OF32>
__device__ __forceinline__ void gemm_body(const void* __restrict__ A, const void* __restrict__ W,
                                          void* __restrict__ C, int M, int N, int K) {
    const int wave = threadIdx.x >> 6;
    const int lane = threadIdx.x & 63;
    const int r = lane & 15;
    const int quad = lane >> 4;
    const int m0 = blockIdx.y * 64 + wave * 16;
    const int n0 = blockIdx.x * 64;

    f32x4 acc[4] = {};
    const size_t aoff = (size_t)(m0 + r) * K + quad * 8;
    const size_t woff = (size_t)(n0 + r) * K + quad * 8;

    for (int k0 = 0; k0 < K; k0 += 32) {
        bf16x8 a = load8<AF32>(A, aoff + k0);
#pragma unroll
        for (int ns = 0; ns < 4; ++ns) {
            bf16x8 b = load8<WF32>(W, woff + (size_t)(ns * 16) * K + k0);
            acc[ns] = __builtin_amdgcn_mfma_f32_16x16x32_bf16(a, b, acc[ns], 0, 0, 0);
        }
    }

#pragma unroll
    for (int ns = 0; ns < 4; ++ns) {
#pragma unroll
        for (int reg = 0; reg < 4; ++reg) {
            int m = m0 + quad * 4 + reg;
            int n = n0 + ns * 16 + r;
            if constexpr (OF32) ((float*)C)[(size_t)m * N + n] = acc[ns][reg];
            else ((__hip_bfloat16*)C)[(size_t)m * N + n] = __float2bfloat16(acc[ns][reg]);
        }
    }
}

__global__ __launch_bounds__(256) void gemm_bt(const void* __restrict__ A, const void* __restrict__ W,
                                               void* __restrict__ C, int M, int N, int K,
                                               const int* __restrict__ flagp, int mode) {
    const int bf = *flagp;
    if (bf) {
        gemm_body<false, false, false>(A, W, C, M, N, K);
    } else if (mode == 0) {
        gemm_body<true, true, false>(A, W, C, M, N, K);
    } else {
        gemm_body<false, true, true>(A, W, C, M, N, K);
    }
}

// ---------------------------------------------------------------------------
// In-place RoPE + RMSNorm on bf16 rows. Row (bs,h) at base + bs*ld + h*D.
// One wave per row; lane d handles pair (d, d+64).
// ---------------------------------------------------------------------------
__global__ __launch_bounds__(256) void rope_rms(__hip_bfloat16* __restrict__ qk,
                                                const void* __restrict__ cosp,
                                                const void* __restrict__ sinp,
                                                int NH, int ld, const int* __restrict__ flagp) {
    const int bf = *flagp;
    const int wave = threadIdx.x >> 6;
    const int lane = threadIdx.x & 63;
    const int row = blockIdx.x * 4 + wave;   // row = bs*NH + h
    const int h = row % NH;
    const int bs = row / NH;
    const int s = bs % S_;

    __hip_bfloat16* p = qk + (size_t)bs * ld + h * D_;
    float x1 = __bfloat162float(p[lane]);
    float x2 = __bfloat162float(p[lane + 64]);
    float c, sn, eps;
    if (bf) {
        c   = __bfloat162float(((const __hip_bfloat16*)cosp)[s * 64 + lane]);
        sn  = __bfloat162float(((const __hip_bfloat16*)sinp)[s * 64 + lane]);
        eps = 0.0078125f;
    } else {
        c   = ((const float*)cosp)[s * 64 + lane];
        sn  = ((const float*)sinp)[s * 64 + lane];
        eps = 1.1920929e-07f;
    }
    float y1 = x1 * c + x2 * sn;
    float y2 = x2 * c - x1 * sn;
    float ss = y1 * y1 + y2 * y2;
#pragma unroll
    for (int m = 1; m < 64; m <<= 1) ss += __shfl_xor(ss, m, 64);
    float rinv = rsqrtf(ss * (1.0f / 128.0f) + eps);
    p[lane]      = __float2bfloat16(y1 * rinv);
    p[lane + 64] = __float2bfloat16(y2 * rinv);
}

// ---------------------------------------------------------------------------
// Flash attention (MFMA). Block = 4 waves; 64 q-rows of one (b,h).
// Q rows at Q + (b*S+q)*ldq + h*D; K rows at K + (b*S+key)*ldkv + kvh*D;
// V likewise; O rows at O + (b*S+q)*ldo + h*D.
// ---------------------------------------------------------------------------
#define KT_ 32
#define LDK 136
#define LDP 40

__global__ __launch_bounds__(256) void attn_flash(const __hip_bfloat16* __restrict__ Q,
                                                  const __hip_bfloat16* __restrict__ K,
                                                  const __hip_bfloat16* __restrict__ V,
                                                  __hip_bfloat16* __restrict__ O,
                                                  int ldq, int ldkv, int ldo) {
    __shared__ unsigned short Ks[KT_][LDK];        // 8704 B
    __shared__ unsigned short Vt[D_ * KT_];        // 8192 B
    __shared__ __hip_bfloat16 Pb[4][16][LDP];      // 5120 B

    const int tid = threadIdx.x;
    const int w = tid >> 6;
    const int lane = tid & 63;
    const int r = lane & 15;
    const int quad = lane >> 4;

    const int qt = gridDim.x - 1 - blockIdx.x;     // big-work tiles dispatch first
    const int q0 = qt * 64;
    const int bh = blockIdx.y;
    const int h = bh % H_;
    const int b = bh / H_;
    const int kvh = h >> 2;

    const int qw_lo = q0 + w * 16;
    const int qw_hi = qw_lo + 15;
    const bf16_t* qptr = (const bf16_t*)Q + (size_t)(b * S_ + qw_lo + r) * ldq + h * D_ + quad * 8;
    bf16x8 qf[4];
#pragma unroll
    for (int c = 0; c < 4; ++c) qf[c] = *(const bf16x8*)(qptr + c * 32);

    f32x4 oacc[8] = {};
    float m_i[4], l_i[4];
#pragma unroll
    for (int g = 0; g < 4; ++g) { m_i[g] = -3e38f; l_i[g] = 0.f; }

    const bf16_t* Kg = (const bf16_t*)K + (size_t)b * S_ * ldkv + kvh * D_;
    const bf16_t* Vg = (const bf16_t*)V + (size_t)b * S_ * ldkv + kvh * D_;

    const int ntiles = q0 / KT_ + 2;
    const float scale = 0.08838834764831845f;      // D^-0.5

    for (int kt = 0; kt < ntiles; ++kt) {
        const int k0 = kt * KT_;
        __syncthreads();
#pragma unroll
        for (int i = 0; i < 2; ++i) {
            const int c = tid + i * 256;
            const int key = c >> 4;                // 0..31
            const int dc = c & 15;                 // dim chunk of 8
            const size_t goff = (size_t)(k0 + key) * ldkv + dc * 8;
            *(uint4*)&Ks[key][dc * 8] = *(const uint4*)(Kg + goff);
            union { uint4 u; unsigned short s[8]; } vv;
            vv.u = *(const uint4*)(Vg + goff);
            const int sw = dc & 3;
#pragma unroll
            for (int j = 0; j < 8; ++j) {
                const int d = dc * 8 + j;
                const int cb = (key >> 3) ^ ((j >> 1) & 3) ^ sw;
                Vt[d * KT_ + cb * 8 + (key & 7)] = vv.s[j];
            }
        }
        __syncthreads();
        if (k0 > qw_hi) continue;                  // fully masked for this wave

        // ---- QK^T: S[16 x 32] ----
        f32x4 s0 = {}, s1 = {};
#pragma unroll
        for (int c = 0; c < 4; ++c) {
            bf16x8 kb0 = *(const bf16x8*)&Ks[r][c * 32 + quad * 8];
            bf16x8 kb1 = *(const bf16x8*)&Ks[16 + r][c * 32 + quad * 8];
            s0 = __builtin_amdgcn_mfma_f32_16x16x32_bf16(qf[c], kb0, s0, 0, 0, 0);
            s1 = __builtin_amdgcn_mfma_f32_16x16x32_bf16(qf[c], kb1, s1, 0, 0, 0);
        }

        const bool bnd = (k0 + KT_ - 1) > qw_lo;
        float mt[4];
#pragma unroll
        for (int g = 0; g < 4; ++g) {
            s0[g] *= scale;
            s1[g] *= scale;
            if (bnd) {
                const int qrow = qw_lo + quad * 4 + g;
                if (k0 + r > qrow)      s0[g] = -3e38f;
                if (k0 + 16 + r > qrow) s1[g] = -3e38f;
            }
            mt[g] = fmaxf(s0[g], s1[g]);
        }
#pragma unroll
        for (int msk = 1; msk < 16; msk <<= 1) {
#pragma unroll
            for (int g = 0; g < 4; ++g) mt[g] = fmaxf(mt[g], __shfl_xor(mt[g], msk, 64));
        }
        float al[4], rs[4];
#pragma unroll
        for (int g = 0; g < 4; ++g) {
            const float mn = fmaxf(m_i[g], mt[g]);
            al[g] = __expf(m_i[g] - mn);
            m_i[g] = mn;
            const float p0 = __expf(s0[g] - mn);
            const float p1 = __expf(s1[g] - mn);
            s0[g] = p0;
            s1[g] = p1;
            rs[g] = p0 + p1;
#pragma unroll
            for (int ns = 0; ns < 8; ++ns) oacc[ns][g] *= al[g];
        }
#pragma unroll
        for (int msk = 1; msk < 16; msk <<= 1) {
#pragma unroll
            for (int g = 0; g < 4; ++g) rs[g] += __shfl_xor(rs[g], msk, 64);
        }
#pragma unroll
        for (int g = 0; g < 4; ++g) l_i[g] = l_i[g] * al[g] + rs[g];

        // ---- P: C-layout -> LDS -> A-layout ----
#pragma unroll
        for (int g = 0; g < 4; ++g) {
            const int row = quad * 4 + g;
            Pb[w][row][r]      = __float2bfloat16(s0[g]);
            Pb[w][row][16 + r] = __float2bfloat16(s1[g]);
        }
        bf16x8 pf = *(const bf16x8*)&Pb[w][r][quad * 8];

        // ---- PV ----
#pragma unroll
        for (int ns = 0; ns < 8; ++ns) {
            const int d = ns * 16 + r;
            const int cb = quad ^ ((r >> 1) & 3) ^ ((2 * ns + (r >> 3)) & 3);
            bf16x8 vf = *(const bf16x8*)&Vt[d * KT_ + cb * 8];
            oacc[ns] = __builtin_amdgcn_mfma_f32_16x16x32_bf16(pf, vf, oacc[ns], 0, 0, 0);
        }
    }

#pragma unroll
    for (int g = 0; g < 4; ++g) {
        const float inv = 1.0f / l_i[g];
        const int qrow = qw_lo + quad * 4 + g;
        __hip_bfloat16* op = O + (size_t)(b * S_ + qrow) * ldo + h * D_;
#pragma unroll
        for (int ns = 0; ns < 8; ++ns)
            op[ns * 16 + r] = __float2bfloat16(oacc[ns][g] * inv);
    }
}

// ---------------------------------------------------------------------------
extern "C" void kernel_launch(void* const* d_in, const int* in_sizes, int n_in,
                              void* d_out, int out_size, void* d_ws, size_t ws_size,
                              hipStream_t stream) {
    const void* x    = d_in[0];
    const void* cosp = d_in[1];
    const void* sinp = d_in[2];
    const void* Wq   = d_in[3];
    const void* Wk   = d_in[4];
    const void* Wv   = d_in[5];
    const void* Wo   = d_in[6];

    const int M = B_ * S_;                 // 4096
    const size_t MB = 1ull << 20;

    if (ws_size >= 28 * MB + 64) {
        // Fast path. ws: [0,16M)=xb then ao; [16M,28M)=Wqkv then Wo; flag at 28M.
        // d_out: qkv bf16 [4096,3072] (24 MB), then final output.
        char* ws = (char*)d_ws;
        bf16_t* xb = (bf16_t*)ws;
        bf16_t* wb = (bf16_t*)(ws + 16 * MB);
        bf16_t* wo = (bf16_t*)(ws + 16 * MB);
        bf16_t* ao = (bf16_t*)ws;
        int* flag  = (int*)(ws + 28 * MB);
        bf16_t* qkv = (bf16_t*)d_out;

        detect_dtype<<<1, 64, 0, stream>>>((const unsigned*)x, flag);

        // convert x, Wq, Wk, Wv -> bf16 (Wqkv contiguous [3072, 2048])
        Cseg sx{x,  xb,                          (B_ * S_ * HID_) / 8};
        Cseg sq{Wq, wb,                          (H_ * D_ * HID_) / 8};
        Cseg sk{Wk, wb + (size_t)2048 * HID_,    (HKV_ * D_ * HID_) / 8};
        Cseg sv{Wv, wb + (size_t)2560 * HID_,    (HKV_ * D_ * HID_) / 8};
        convert_bf16<<<dim3(4096, 4), 256, 0, stream>>>(sx, sq, sk, sv, flag);

        // Fused QKV projection: [4096,2048] x [3072,2048]^T -> qkv [4096,3072]
        gemm_lds<<<dim3(3072 / 128, M / 128), 256, 0, stream>>>(xb, wb, qkv, M, 3072, HID_, flag, 0);

        // convert Wo -> bf16 (xb/wb regions dead for Wqkv; wo overlays wb)
        Cseg so{Wo, wo, (HID_ * H_ * D_) / 8};
        convert_bf16<<<dim3(2048, 1), 256, 0, stream>>>(so, so, so, so, flag);

        // RoPE + RMSNorm in-place: q cols [0,2048), k cols [2048,2560)
        rope_rms<<<(B_ * S_ * H_) / 4, 256, 0, stream>>>((__hip_bfloat16*)qkv, cosp, sinp, H_, 3072, flag);
        rope_rms<<<(B_ * S_ * HKV_) / 4, 256, 0, stream>>>((__hip_bfloat16*)(qkv + 2048), cosp, sinp, HKV_, 3072, flag);

        // Flash attention: Q/K/V strided in qkv; O -> ao (xb dead)
        attn_flash<<<dim3(S_ / 64, B_ * H_), 256, 0, stream>>>(
            (const __hip_bfloat16*)qkv, (const __hip_bfloat16*)(qkv + 2048),
            (const __hip_bfloat16*)(qkv + 2560), (__hip_bfloat16*)ao, 3072, 3072, 2048);

        // Output projection: ao x Wo^T -> d_out (fp32 if flag=0)
        gemm_lds<<<dim3(HID_ / 128, M / 128), 256, 0, stream>>>(ao, wo, d_out, M, HID_, H_ * D_, flag, 1);
    } else {
        // Fallback: round-4 proven path (ws >= 16 MB + 4).
        __hip_bfloat16* qb = (__hip_bfloat16*)d_ws;
        int* flag = (int*)((char*)d_ws + (size_t)M * (H_ * D_) * sizeof(__hip_bfloat16));
        __hip_bfloat16* kb = (__hip_bfloat16*)d_out;
        __hip_bfloat16* vb = kb + (size_t)M * (HKV_ * D_);

        detect_dtype<<<1, 64, 0, stream>>>((const unsigned*)x, flag);

        gemm_bt<<<dim3((H_ * D_) / 64, M / 64), 256, 0, stream>>>(x, Wq, qb, M, H_ * D_, HID_, flag, 0);
        gemm_bt<<<dim3((HKV_ * D_) / 64, M / 64), 256, 0, stream>>>(x, Wk, kb, M, HKV_ * D_, HID_, flag, 0);
        gemm_bt<<<dim3((HKV_ * D_) / 64, M / 64), 256, 0, stream>>>(x, Wv, vb, M, HKV_ * D_, HID_, flag, 0);

        rope_rms<<<(B_ * S_ * H_) / 4, 256, 0, stream>>>(qb, cosp, sinp, H_, H_ * D_, flag);
        rope_rms<<<(B_ * S_ * HKV_) / 4, 256, 0, stream>>>(kb, cosp, sinp, HKV_, HKV_ * D_, flag);

        attn_flash<<<dim3(S_ / 64, B_ * H_), 256, 0, stream>>>(qb, kb, vb, qb, H_ * D_, HKV_ * D_, H_ * D_);

        gemm_bt<<<dim3(HID_ / 64, M / 64), 256, 0, stream>>>(qb, Wo, d_out, M, HID_, H_ * D_, flag, 1);
    }
}

// Round 6
// 446.048 us; speedup vs baseline: 12.7020x; 1.1802x over previous
//
#include <hip/hip_runtime.h>
#include <hip/hip_bf16.h>

// Problem constants
#define B_  2
#define S_  2048
#define HID_ 2048
#define H_  16
#define HKV_ 4
#define D_  128

typedef __bf16 bf16_t;
typedef bf16_t bf16x8 __attribute__((ext_vector_type(8)));
typedef float f32x4 __attribute__((ext_vector_type(4)));

typedef __attribute__((address_space(3))) unsigned int lds_u32_t;
typedef const __attribute__((address_space(1))) unsigned int glob_u32_t;

// async global->LDS, 16 B per lane; LDS dest = wave-uniform base + lane*16
__device__ __forceinline__ void gl2lds16(const bf16_t* g, bf16_t* l) {
    __builtin_amdgcn_global_load_lds((glob_u32_t*)g, (lds_u32_t*)l, 16, 0, 0);
}

// ---------------------------------------------------------------------------
// Runtime dtype detection: flag=1 if inputs are bf16, 0 if fp32.
// ---------------------------------------------------------------------------
__global__ void detect_dtype(const unsigned* __restrict__ x, int* __restrict__ flag) {
    int lane = threadIdx.x;
    int c = 0;
#pragma unroll
    for (int i = 0; i < 16; ++i) {
        unsigned w = x[lane * 16 + i];
        unsigned e = (w >> 7) & 0xFF;
        c += (e >= 117 && e <= 137) ? 1 : 0;
    }
#pragma unroll
    for (int m = 1; m < 64; m <<= 1) c += __shfl_xor(c, m, 64);
    if (lane == 0) *flag = (c >= 512) ? 1 : 0;
}

// ---------------------------------------------------------------------------
// Conversion pass: src (fp32 or bf16 per flag) -> bf16 dst. 8 elems/thread.
// ---------------------------------------------------------------------------
struct Cseg { const void* src; bf16_t* dst; int n8; };

__global__ __launch_bounds__(256) void convert_bf16(Cseg s0, Cseg s1, Cseg s2, Cseg s3,
                                                    const int* __restrict__ flagp) {
    Cseg s = (blockIdx.y == 0) ? s0 : (blockIdx.y == 1) ? s1 : (blockIdx.y == 2) ? s2 : s3;
    const int i = blockIdx.x * 256 + threadIdx.x;
    if (i >= s.n8) return;
    if (*flagp) {
        ((uint4*)s.dst)[i] = ((const uint4*)s.src)[i];
    } else {
        const float4* p = (const float4*)s.src + (size_t)i * 2;
        float4 u = p[0], v = p[1];
        bf16x8 r;
        r[0] = (bf16_t)u.x; r[1] = (bf16_t)u.y; r[2] = (bf16_t)u.z; r[3] = (bf16_t)u.w;
        r[4] = (bf16_t)v.x; r[5] = (bf16_t)v.y; r[6] = (bf16_t)v.z; r[7] = (bf16_t)v.w;
        *(bf16x8*)(s.dst + (size_t)i * 8) = r;
    }
}

// ---------------------------------------------------------------------------
// m97-structure GEMM: C[m,n] = sum_k A[m,k]*W[n,k], A/W bf16 row-major.
// 128x128 tile, BK=32, LDS staging via global_load_lds width=16.
// ---------------------------------------------------------------------------
__global__ __launch_bounds__(256) void gemm_lds(const bf16_t* __restrict__ A,
                                                const bf16_t* __restrict__ W,
                                                void* __restrict__ C,
                                                int M, int N, int K,
                                                const int* __restrict__ flagp, int osel) {
    __shared__ bf16_t As[128 * 32];
    __shared__ bf16_t Bs[128 * 32];

    const int tid = threadIdx.x;
    const int w = tid >> 6;
    const int lane = tid & 63;
    const int r = lane & 15;
    const int quad = lane >> 4;
    const int m0 = blockIdx.y * 128;
    const int n0 = blockIdx.x * 128;
    const bool of32 = osel && (*flagp == 0);

    const int mh = (w & 1) * 64;
    const int nh = (w >> 1) * 64;

    const int c0 = w * 2;
    const int srow = lane >> 2;
    const int scol = (lane & 3) * 8;
    const bf16_t* Ag0 = A + (size_t)(m0 + c0 * 16 + srow) * K + scol;
    const bf16_t* Ag1 = A + (size_t)(m0 + c0 * 16 + 16 + srow) * K + scol;
    const bf16_t* Wg0 = W + (size_t)(n0 + c0 * 16 + srow) * K + scol;
    const bf16_t* Wg1 = W + (size_t)(n0 + c0 * 16 + 16 + srow) * K + scol;
    bf16_t* Al0 = As + c0 * 512;
    bf16_t* Al1 = As + (c0 + 1) * 512;
    bf16_t* Bl0 = Bs + c0 * 512;
    bf16_t* Bl1 = Bs + (c0 + 1) * 512;

    f32x4 acc[4][4] = {};

    for (int k0 = 0; k0 < K; k0 += 32) {
        __syncthreads();
        gl2lds16(Ag0 + k0, Al0);
        gl2lds16(Ag1 + k0, Al1);
        gl2lds16(Wg0 + k0, Bl0);
        gl2lds16(Wg1 + k0, Bl1);
        __syncthreads();

        bf16x8 a[4], b[4];
#pragma unroll
        for (int mi = 0; mi < 4; ++mi)
            a[mi] = *(const bf16x8*)&As[(mh + mi * 16 + r) * 32 + quad * 8];
#pragma unroll
        for (int ni = 0; ni < 4; ++ni)
            b[ni] = *(const bf16x8*)&Bs[(nh + ni * 16 + r) * 32 + quad * 8];
#pragma unroll
        for (int mi = 0; mi < 4; ++mi)
#pragma unroll
            for (int ni = 0; ni < 4; ++ni)
                acc[mi][ni] = __builtin_amdgcn_mfma_f32_16x16x32_bf16(a[mi], b[ni], acc[mi][ni], 0, 0, 0);
    }

#pragma unroll
    for (int mi = 0; mi < 4; ++mi) {
#pragma unroll
        for (int ni = 0; ni < 4; ++ni) {
#pragma unroll
            for (int g = 0; g < 4; ++g) {
                const int row = m0 + mh + mi * 16 + quad * 4 + g;
                const int col = n0 + nh + ni * 16 + r;
                if (of32) ((float*)C)[(size_t)row * N + col] = acc[mi][ni][g];
                else ((__hip_bfloat16*)C)[(size_t)row * N + col] = __float2bfloat16(acc[mi][ni][g]);
            }
        }
    }
}

// ---------------------------------------------------------------------------
// Fallback direct-from-global GEMM (proven path).
// ---------------------------------------------------------------------------
template <bool F32>
__device__ __forceinline__ bf16x8 load8(const void* base, size_t off) {
    bf16x8 r;
    if constexpr (F32) {
        const float4* p = (const float4*)((const float*)base + off);
        float4 u = p[0], v = p[1];
        r[0] = (bf16_t)u.x; r[1] = (bf16_t)u.y; r[2] = (bf16_t)u.z; r[3] = (bf16_t)u.w;
        r[4] = (bf16_t)v.x; r[5] = (bf16_t)v.y; r[6] = (bf16_t)v.z; r[7] = (bf16_t)v.w;
    } else {
        r = *(const bf16x8*)((const bf16_t*)base + off);
    }
    return r;
}

template <bool AF32, bool WF32, bool OF32>
__device__ __forceinline__ void gemm_body(const void* __restrict__ A, const void* __restrict__ W,
                                          void* __restrict__ C, int M, int N, int K) {
    const int wave = threadIdx.x >> 6;
    const int lane = threadIdx.x & 63;
    const int r = lane & 15;
    const int quad = lane >> 4;
    const int m0 = blockIdx.y * 64 + wave * 16;
    const int n0 = blockIdx.x * 64;

    f32x4 acc[4] = {};
    const size_t aoff = (size_t)(m0 + r) * K + quad * 8;
    const size_t woff = (size_t)(n0 + r) * K + quad * 8;

    for (int k0 = 0; k0 < K; k0 += 32) {
        bf16x8 a = load8<AF32>(A, aoff + k0);
#pragma unroll
        for (int ns = 0; ns < 4; ++ns) {
            bf16x8 b = load8<WF32>(W, woff + (size_t)(ns * 16) * K + k0);
            acc[ns] = __builtin_amdgcn_mfma_f32_16x16x32_bf16(a, b, acc[ns], 0, 0, 0);
        }
    }

#pragma unroll
    for (int ns = 0; ns < 4; ++ns) {
#pragma unroll
        for (int reg = 0; reg < 4; ++reg) {
            int m = m0 + quad * 4 + reg;
            int n = n0 + ns * 16 + r;
            if constexpr (OF32) ((float*)C)[(size_t)m * N + n] = acc[ns][reg];
            else ((__hip_bfloat16*)C)[(size_t)m * N + n] = __float2bfloat16(acc[ns][reg]);
        }
    }
}

__global__ __launch_bounds__(256) void gemm_bt(const void* __restrict__ A, const void* __restrict__ W,
                                               void* __restrict__ C, int M, int N, int K,
                                               const int* __restrict__ flagp, int mode) {
    const int bf = *flagp;
    if (bf) {
        gemm_body<false, false, false>(A, W, C, M, N, K);
    } else if (mode == 0) {
        gemm_body<true, true, false>(A, W, C, M, N, K);
    } else {
        gemm_body<false, true, true>(A, W, C, M, N, K);
    }
}

// ---------------------------------------------------------------------------
// In-place RoPE + RMSNorm on bf16 rows. Row (bs,h) at base + bs*ld + h*D.
// ---------------------------------------------------------------------------
__global__ __launch_bounds__(256) void rope_rms(__hip_bfloat16* __restrict__ qk,
                                                const void* __restrict__ cosp,
                                                const void* __restrict__ sinp,
                                                int NH, int ld, const int* __restrict__ flagp) {
    const int bf = *flagp;
    const int wave = threadIdx.x >> 6;
    const int lane = threadIdx.x & 63;
    const int row = blockIdx.x * 4 + wave;   // row = bs*NH + h
    const int h = row % NH;
    const int bs = row / NH;
    const int s = bs % S_;

    __hip_bfloat16* p = qk + (size_t)bs * ld + h * D_;
    float x1 = __bfloat162float(p[lane]);
    float x2 = __bfloat162float(p[lane + 64]);
    float c, sn, eps;
    if (bf) {
        c   = __bfloat162float(((const __hip_bfloat16*)cosp)[s * 64 + lane]);
        sn  = __bfloat162float(((const __hip_bfloat16*)sinp)[s * 64 + lane]);
        eps = 0.0078125f;
    } else {
        c   = ((const float*)cosp)[s * 64 + lane];
        sn  = ((const float*)sinp)[s * 64 + lane];
        eps = 1.1920929e-07f;
    }
    float y1 = x1 * c + x2 * sn;
    float y2 = x2 * c - x1 * sn;
    float ss = y1 * y1 + y2 * y2;
#pragma unroll
    for (int m = 1; m < 64; m <<= 1) ss += __shfl_xor(ss, m, 64);
    float rinv = rsqrtf(ss * (1.0f / 128.0f) + eps);
    p[lane]      = __float2bfloat16(y1 * rinv);
    p[lane + 64] = __float2bfloat16(y2 * rinv);
}

// ---------------------------------------------------------------------------
// Flash attention v2 (MFMA, GQA-shared staging).
// Block = 4 waves = the 4 q-heads of one (b, kvh) GQA group; all waves share
// one staged K/V tile and cover the SAME 32 q-rows (perfect intra-block
// balance). Wave w = head kvh*4+w, 2 row-frags of 16 q-rows each.
// Softmax in exp2 domain (scale pre-multiplied by log2e); row-sum l computed
// by an extra ones-column MFMA (no shuffle reduction); O-rescale is
// ballot-gated (skipped when the running max doesn't change).
// Vt swizzle identical to the correctness-proven round-5 scheme.
// O may alias Q: block reads only its own (rows 32 x cols kvh*512..+512)
// region into registers at start, writes exactly that region at the end.
// ---------------------------------------------------------------------------
#define KT_ 32
#define LDK 136
#define LDP 40

__global__ __launch_bounds__(256, 2) void attn_flash2(const __hip_bfloat16* __restrict__ Q,
                                                      const __hip_bfloat16* __restrict__ K,
                                                      const __hip_bfloat16* __restrict__ V,
                                                      __hip_bfloat16* __restrict__ O,
                                                      int ldq, int ldkv, int ldo) {
    __shared__ unsigned short Ks[KT_][LDK];          // 8704 B
    __shared__ unsigned short Vt[D_ * KT_];          // 8192 B
    __shared__ __hip_bfloat16 Pb[4][2][16][LDP];     // 10240 B

    const int tid = threadIdx.x;
    const int w = tid >> 6;
    const int lane = tid & 63;
    const int r = lane & 15;
    const int quad = lane >> 4;

    const int qt = gridDim.x - 1 - blockIdx.x;       // big-work blocks dispatch first
    const int q0 = qt * 32;
    const int gy = blockIdx.y;                       // b*HKV + kvh
    const int kvh = gy % HKV_;
    const int b = gy / HKV_;
    const int h = kvh * 4 + w;                       // this wave's q-head

    // Q fragments: 2 row-tiles x 4 k-chunks
    bf16x8 qf[2][4];
#pragma unroll
    for (int t = 0; t < 2; ++t) {
        const bf16_t* qp = (const bf16_t*)Q + (size_t)(b * S_ + q0 + t * 16 + r) * ldq + h * D_ + quad * 8;
#pragma unroll
        for (int c = 0; c < 4; ++c) qf[t][c] = *(const bf16x8*)(qp + c * 32);
    }

    f32x4 oacc[2][8] = {};
    f32x4 lacc[2] = {};
    float m_i[2][4];
#pragma unroll
    for (int t = 0; t < 2; ++t)
#pragma unroll
        for (int g = 0; g < 4; ++g) m_i[t][g] = -3e38f;

    const bf16_t* Kg = (const bf16_t*)K + (size_t)b * S_ * ldkv + kvh * D_;
    const bf16_t* Vg = (const bf16_t*)V + (size_t)b * S_ * ldkv + kvh * D_;

    bf16x8 ones;
#pragma unroll
    for (int j = 0; j < 8; ++j) ones[j] = (bf16_t)1.0f;

    const float SC2 = 0.08838834764831845f * 1.4426950408889634f;  // D^-0.5 * log2(e)

    for (int kt = 0; kt <= qt; ++kt) {
        const int k0 = kt * KT_;
        __syncthreads();
        // ---- stage K and V tiles (shared by all 4 heads) ----
#pragma unroll
        for (int i = 0; i < 2; ++i) {
            const int c = tid + i * 256;
            const int key = c >> 4;                  // 0..31
            const int dc = c & 15;                   // dim chunk of 8
            const size_t goff = (size_t)(k0 + key) * ldkv + dc * 8;
            *(uint4*)&Ks[key][dc * 8] = *(const uint4*)(Kg + goff);
            union { uint4 u; unsigned short s[8]; } vv;
            vv.u = *(const uint4*)(Vg + goff);
            const int sw = dc & 3;
#pragma unroll
            for (int j = 0; j < 8; ++j) {
                const int d = dc * 8 + j;
                const int cb = (key >> 3) ^ ((j >> 1) & 3) ^ sw;
                Vt[d * KT_ + cb * 8 + (key & 7)] = vv.s[j];
            }
        }
        __syncthreads();

        // ---- QK^T: S[2][16 x 32]; K-frags shared across row-tiles ----
        f32x4 s0[2] = {}, s1[2] = {};
#pragma unroll
        for (int c = 0; c < 4; ++c) {
            bf16x8 kb0 = *(const bf16x8*)&Ks[r][c * 32 + quad * 8];
            bf16x8 kb1 = *(const bf16x8*)&Ks[16 + r][c * 32 + quad * 8];
#pragma unroll
            for (int t = 0; t < 2; ++t) {
                s0[t] = __builtin_amdgcn_mfma_f32_16x16x32_bf16(qf[t][c], kb0, s0[t], 0, 0, 0);
                s1[t] = __builtin_amdgcn_mfma_f32_16x16x32_bf16(qf[t][c], kb1, s1[t], 0, 0, 0);
            }
        }

        const bool bnd = (kt == qt);
#pragma unroll
        for (int t = 0; t < 2; ++t) {
            float mt[4];
#pragma unroll
            for (int g = 0; g < 4; ++g) {
                s0[t][g] *= SC2;
                s1[t][g] *= SC2;
                if (bnd) {
                    const int qrow = q0 + t * 16 + quad * 4 + g;
                    if (k0 + r > qrow)      s0[t][g] = -1e38f;
                    if (k0 + 16 + r > qrow) s1[t][g] = -1e38f;
                }
                mt[g] = fmaxf(s0[t][g], s1[t][g]);
            }
#pragma unroll
            for (int msk = 1; msk < 16; msk <<= 1) {
#pragma unroll
                for (int g = 0; g < 4; ++g) mt[g] = fmaxf(mt[g], __shfl_xor(mt[g], msk, 64));
            }
            // ballot-gated rescale: only when some row's max moved up
            bool upd = false;
#pragma unroll
            for (int g = 0; g < 4; ++g) upd |= (mt[g] > m_i[t][g]);
            if (__ballot(upd)) {
#pragma unroll
                for (int g = 0; g < 4; ++g) {
                    const float mn = fmaxf(m_i[t][g], mt[g]);
                    const float al = exp2f(m_i[t][g] - mn);
                    m_i[t][g] = mn;
                    lacc[t][g] *= al;
#pragma unroll
                    for (int ns = 0; ns < 8; ++ns) oacc[t][ns][g] *= al;
                }
            }
            // p = 2^(s - m); store P in A-layout via LDS (same-wave roundtrip)
#pragma unroll
            for (int g = 0; g < 4; ++g) {
                const float p0 = exp2f(s0[t][g] - m_i[t][g]);
                const float p1 = exp2f(s1[t][g] - m_i[t][g]);
                const int row = quad * 4 + g;
                Pb[w][t][row][r]      = __float2bfloat16(p0);
                Pb[w][t][row][16 + r] = __float2bfloat16(p1);
            }
        }

        bf16x8 pf0 = *(const bf16x8*)&Pb[w][0][r][quad * 8];
        bf16x8 pf1 = *(const bf16x8*)&Pb[w][1][r][quad * 8];

        // row-sum l via ones-column MFMA (no shuffle reduce)
        lacc[0] = __builtin_amdgcn_mfma_f32_16x16x32_bf16(pf0, ones, lacc[0], 0, 0, 0);
        lacc[1] = __builtin_amdgcn_mfma_f32_16x16x32_bf16(pf1, ones, lacc[1], 0, 0, 0);

        // ---- PV: V-frags shared across row-tiles ----
#pragma unroll
        for (int ns = 0; ns < 8; ++ns) {
            const int d = ns * 16 + r;
            const int cb = quad ^ ((r >> 1) & 3) ^ ((2 * ns + (r >> 3)) & 3);
            bf16x8 vf = *(const bf16x8*)&Vt[d * KT_ + cb * 8];
            oacc[0][ns] = __builtin_amdgcn_mfma_f32_16x16x32_bf16(pf0, vf, oacc[0][ns], 0, 0, 0);
            oacc[1][ns] = __builtin_amdgcn_mfma_f32_16x16x32_bf16(pf1, vf, oacc[1][ns], 0, 0, 0);
        }
    }

    // ---- epilogue: O / l, store ----
#pragma unroll
    for (int t = 0; t < 2; ++t) {
#pragma unroll
        for (int g = 0; g < 4; ++g) {
            const float inv = 1.0f / lacc[t][g];
            const int qrow = q0 + t * 16 + quad * 4 + g;
            __hip_bfloat16* op = O + (size_t)(b * S_ + qrow) * ldo + h * D_;
#pragma unroll
            for (int ns = 0; ns < 8; ++ns)
                op[ns * 16 + r] = __float2bfloat16(oacc[t][ns][g] * inv);
        }
    }
}

// ---------------------------------------------------------------------------
extern "C" void kernel_launch(void* const* d_in, const int* in_sizes, int n_in,
                              void* d_out, int out_size, void* d_ws, size_t ws_size,
                              hipStream_t stream) {
    const void* x    = d_in[0];
    const void* cosp = d_in[1];
    const void* sinp = d_in[2];
    const void* Wq   = d_in[3];
    const void* Wk   = d_in[4];
    const void* Wv   = d_in[5];
    const void* Wo   = d_in[6];

    const int M = B_ * S_;                 // 4096
    const size_t MB = 1ull << 20;

    if (ws_size >= 28 * MB + 64) {
        // Fast path. ws: [0,16M)=xb then ao; [16M,28M)=Wqkv then Wo; flag at 28M.
        // d_out: qkv bf16 [4096,3072] (24 MB), then final output.
        char* ws = (char*)d_ws;
        bf16_t* xb = (bf16_t*)ws;
        bf16_t* wb = (bf16_t*)(ws + 16 * MB);
        bf16_t* wo = (bf16_t*)(ws + 16 * MB);
        bf16_t* ao = (bf16_t*)ws;
        int* flag  = (int*)(ws + 28 * MB);
        bf16_t* qkv = (bf16_t*)d_out;

        detect_dtype<<<1, 64, 0, stream>>>((const unsigned*)x, flag);

        // convert x, Wq, Wk, Wv -> bf16 (Wqkv contiguous [3072, 2048])
        Cseg sx{x,  xb,                          (B_ * S_ * HID_) / 8};
        Cseg sq{Wq, wb,                          (H_ * D_ * HID_) / 8};
        Cseg sk{Wk, wb + (size_t)2048 * HID_,    (HKV_ * D_ * HID_) / 8};
        Cseg sv{Wv, wb + (size_t)2560 * HID_,    (HKV_ * D_ * HID_) / 8};
        convert_bf16<<<dim3(4096, 4), 256, 0, stream>>>(sx, sq, sk, sv, flag);

        // Fused QKV projection: [4096,2048] x [3072,2048]^T -> qkv [4096,3072]
        gemm_lds<<<dim3(3072 / 128, M / 128), 256, 0, stream>>>(xb, wb, qkv, M, 3072, HID_, flag, 0);

        // convert Wo -> bf16 (wb dead; wo overlays wb)
        Cseg so{Wo, wo, (HID_ * H_ * D_) / 8};
        convert_bf16<<<dim3(2048, 1), 256, 0, stream>>>(so, so, so, so, flag);

        // RoPE + RMSNorm in-place: q cols [0,2048), k cols [2048,2560)
        rope_rms<<<(B_ * S_ * H_) / 4, 256, 0, stream>>>((__hip_bfloat16*)qkv, cosp, sinp, H_, 3072, flag);
        rope_rms<<<(B_ * S_ * HKV_) / 4, 256, 0, stream>>>((__hip_bfloat16*)(qkv + 2048), cosp, sinp, HKV_, 3072, flag);

        // Flash attention v2: Q/K/V strided in qkv; O -> ao (xb dead)
        attn_flash2<<<dim3(S_ / 32, B_ * HKV_), 256, 0, stream>>>(
            (const __hip_bfloat16*)qkv, (const __hip_bfloat16*)(qkv + 2048),
            (const __hip_bfloat16*)(qkv + 2560), (__hip_bfloat16*)ao, 3072, 3072, 2048);

        // Output projection: ao x Wo^T -> d_out (fp32 if flag=0)
        gemm_lds<<<dim3(HID_ / 128, M / 128), 256, 0, stream>>>(ao, wo, d_out, M, HID_, H_ * D_, flag, 1);
    } else {
        // Fallback: proven path (ws >= 16 MB + 4).
        __hip_bfloat16* qb = (__hip_bfloat16*)d_ws;
        int* flag = (int*)((char*)d_ws + (size_t)M * (H_ * D_) * sizeof(__hip_bfloat16));
        __hip_bfloat16* kb = (__hip_bfloat16*)d_out;
        __hip_bfloat16* vb = kb + (size_t)M * (HKV_ * D_);

        detect_dtype<<<1, 64, 0, stream>>>((const unsigned*)x, flag);

        gemm_bt<<<dim3((H_ * D_) / 64, M / 64), 256, 0, stream>>>(x, Wq, qb, M, H_ * D_, HID_, flag, 0);
        gemm_bt<<<dim3((HKV_ * D_) / 64, M / 64), 256, 0, stream>>>(x, Wk, kb, M, HKV_ * D_, HID_, flag, 0);
        gemm_bt<<<dim3((HKV_ * D_) / 64, M / 64), 256, 0, stream>>>(x, Wv, vb, M, HKV_ * D_, HID_, flag, 0);

        rope_rms<<<(B_ * S_ * H_) / 4, 256, 0, stream>>>(qb, cosp, sinp, H_, H_ * D_, flag);
        rope_rms<<<(B_ * S_ * HKV_) / 4, 256, 0, stream>>>(kb, cosp, sinp, HKV_, HKV_ * D_, flag);

        // in-place O over qb is safe: block touches only its own rows x head-cols
        attn_flash2<<<dim3(S_ / 32, B_ * HKV_), 256, 0, stream>>>(qb, kb, vb, qb, H_ * D_, HKV_ * D_, H_ * D_);

        gemm_bt<<<dim3(HID_ / 64, M / 64), 256, 0, stream>>>(qb, Wo, d_out, M, HID_, H_ * D_, flag, 1);
    }
}

// Round 7
// 422.088 us; speedup vs baseline: 13.4231x; 1.0568x over previous
//
#include <hip/hip_runtime.h>
#include <hip/hip_bf16.h>

// Problem constants
#define B_  2
#define S_  2048
#define HID_ 2048
#define H_  16
#define HKV_ 4
#define D_  128

typedef __bf16 bf16_t;
typedef bf16_t bf16x8 __attribute__((ext_vector_type(8)));
typedef float f32x4 __attribute__((ext_vector_type(4)));

typedef __attribute__((address_space(3))) unsigned int lds_u32_t;
typedef const __attribute__((address_space(1))) unsigned int glob_u32_t;

// async global->LDS, 16 B per lane; LDS dest = wave-uniform base + lane*16
__device__ __forceinline__ void gl2lds16(const bf16_t* g, bf16_t* l) {
    __builtin_amdgcn_global_load_lds((glob_u32_t*)g, (lds_u32_t*)l, 16, 0, 0);
}

__device__ __forceinline__ unsigned packbf2(float a, float b) {
    union { bf16_t h[2]; unsigned u; } p;
    p.h[0] = (bf16_t)a;
    p.h[1] = (bf16_t)b;
    return p.u;
}

// ---------------------------------------------------------------------------
// Runtime dtype detection: flag=1 if inputs are bf16, 0 if fp32.
// ---------------------------------------------------------------------------
__global__ void detect_dtype(const unsigned* __restrict__ x, int* __restrict__ flag) {
    int lane = threadIdx.x;
    int c = 0;
#pragma unroll
    for (int i = 0; i < 16; ++i) {
        unsigned w = x[lane * 16 + i];
        unsigned e = (w >> 7) & 0xFF;
        c += (e >= 117 && e <= 137) ? 1 : 0;
    }
#pragma unroll
    for (int m = 1; m < 64; m <<= 1) c += __shfl_xor(c, m, 64);
    if (lane == 0) *flag = (c >= 512) ? 1 : 0;
}

// ---------------------------------------------------------------------------
// Conversion pass: src (fp32 or bf16 per flag) -> bf16 dst. 8 elems/thread.
// ---------------------------------------------------------------------------
struct Cseg { const void* src; bf16_t* dst; int n8; };

__global__ __launch_bounds__(256) void convert_bf16(Cseg s0, Cseg s1, Cseg s2, Cseg s3,
                                                    const int* __restrict__ flagp) {
    Cseg s = (blockIdx.y == 0) ? s0 : (blockIdx.y == 1) ? s1 : (blockIdx.y == 2) ? s2 : s3;
    const int i = blockIdx.x * 256 + threadIdx.x;
    if (i >= s.n8) return;
    if (*flagp) {
        ((uint4*)s.dst)[i] = ((const uint4*)s.src)[i];
    } else {
        const float4* p = (const float4*)s.src + (size_t)i * 2;
        float4 u = p[0], v = p[1];
        bf16x8 r;
        r[0] = (bf16_t)u.x; r[1] = (bf16_t)u.y; r[2] = (bf16_t)u.z; r[3] = (bf16_t)u.w;
        r[4] = (bf16_t)v.x; r[5] = (bf16_t)v.y; r[6] = (bf16_t)v.z; r[7] = (bf16_t)v.w;
        *(bf16x8*)(s.dst + (size_t)i * 8) = r;
    }
}

// ---------------------------------------------------------------------------
// m97-structure GEMM: C[m,n] = sum_k A[m,k]*W[n,k], A/W bf16 row-major.
// 128x128 tile, BK=32, LDS staging via global_load_lds width=16.
// ---------------------------------------------------------------------------
__global__ __launch_bounds__(256) void gemm_lds(const bf16_t* __restrict__ A,
                                                const bf16_t* __restrict__ W,
                                                void* __restrict__ C,
                                                int M, int N, int K,
                                                const int* __restrict__ flagp, int osel) {
    __shared__ bf16_t As[128 * 32];
    __shared__ bf16_t Bs[128 * 32];

    const int tid = threadIdx.x;
    const int w = tid >> 6;
    const int lane = tid & 63;
    const int r = lane & 15;
    const int quad = lane >> 4;
    const int m0 = blockIdx.y * 128;
    const int n0 = blockIdx.x * 128;
    const bool of32 = osel && (*flagp == 0);

    const int mh = (w & 1) * 64;
    const int nh = (w >> 1) * 64;

    const int c0 = w * 2;
    const int srow = lane >> 2;
    const int scol = (lane & 3) * 8;
    const bf16_t* Ag0 = A + (size_t)(m0 + c0 * 16 + srow) * K + scol;
    const bf16_t* Ag1 = A + (size_t)(m0 + c0 * 16 + 16 + srow) * K + scol;
    const bf16_t* Wg0 = W + (size_t)(n0 + c0 * 16 + srow) * K + scol;
    const bf16_t* Wg1 = W + (size_t)(n0 + c0 * 16 + 16 + srow) * K + scol;
    bf16_t* Al0 = As + c0 * 512;
    bf16_t* Al1 = As + (c0 + 1) * 512;
    bf16_t* Bl0 = Bs + c0 * 512;
    bf16_t* Bl1 = Bs + (c0 + 1) * 512;

    f32x4 acc[4][4] = {};

    for (int k0 = 0; k0 < K; k0 += 32) {
        __syncthreads();
        gl2lds16(Ag0 + k0, Al0);
        gl2lds16(Ag1 + k0, Al1);
        gl2lds16(Wg0 + k0, Bl0);
        gl2lds16(Wg1 + k0, Bl1);
        __syncthreads();

        bf16x8 a[4], b[4];
#pragma unroll
        for (int mi = 0; mi < 4; ++mi)
            a[mi] = *(const bf16x8*)&As[(mh + mi * 16 + r) * 32 + quad * 8];
#pragma unroll
        for (int ni = 0; ni < 4; ++ni)
            b[ni] = *(const bf16x8*)&Bs[(nh + ni * 16 + r) * 32 + quad * 8];
#pragma unroll
        for (int mi = 0; mi < 4; ++mi)
#pragma unroll
            for (int ni = 0; ni < 4; ++ni)
                acc[mi][ni] = __builtin_amdgcn_mfma_f32_16x16x32_bf16(a[mi], b[ni], acc[mi][ni], 0, 0, 0);
    }

#pragma unroll
    for (int mi = 0; mi < 4; ++mi) {
#pragma unroll
        for (int ni = 0; ni < 4; ++ni) {
#pragma unroll
            for (int g = 0; g < 4; ++g) {
                const int row = m0 + mh + mi * 16 + quad * 4 + g;
                const int col = n0 + nh + ni * 16 + r;
                if (of32) ((float*)C)[(size_t)row * N + col] = acc[mi][ni][g];
                else ((__hip_bfloat16*)C)[(size_t)row * N + col] = __float2bfloat16(acc[mi][ni][g]);
            }
        }
    }
}

// ---------------------------------------------------------------------------
// Fallback direct-from-global GEMM (proven path).
// ---------------------------------------------------------------------------
template <bool F32>
__device__ __forceinline__ bf16x8 load8(const void* base, size_t off) {
    bf16x8 r;
    if constexpr (F32) {
        const float4* p = (const float4*)((const float*)base + off);
        float4 u = p[0], v = p[1];
        r[0] = (bf16_t)u.x; r[1] = (bf16_t)u.y; r[2] = (bf16_t)u.z; r[3] = (bf16_t)u.w;
        r[4] = (bf16_t)v.x; r[5] = (bf16_t)v.y; r[6] = (bf16_t)v.z; r[7] = (bf16_t)v.w;
    } else {
        r = *(const bf16x8*)((const bf16_t*)base + off);
    }
    return r;
}

template <bool AF32, bool WF32, bool OF32>
__device__ __forceinline__ void gemm_body(const void* __restrict__ A, const void* __restrict__ W,
                                          void* __restrict__ C, int M, int N, int K) {
    const int wave = threadIdx.x >> 6;
    const int lane = threadIdx.x & 63;
    const int r = lane & 15;
    const int quad = lane >> 4;
    const int m0 = blockIdx.y * 64 + wave * 16;
    const int n0 = blockIdx.x * 64;

    f32x4 acc[4] = {};
    const size_t aoff = (size_t)(m0 + r) * K + quad * 8;
    const size_t woff = (size_t)(n0 + r) * K + quad * 8;

    for (int k0 = 0; k0 < K; k0 += 32) {
        bf16x8 a = load8<AF32>(A, aoff + k0);
#pragma unroll
        for (int ns = 0; ns < 4; ++ns) {
            bf16x8 b = load8<WF32>(W, woff + (size_t)(ns * 16) * K + k0);
            acc[ns] = __builtin_amdgcn_mfma_f32_16x16x32_bf16(a, b, acc[ns], 0, 0, 0);
        }
    }

#pragma unroll
    for (int ns = 0; ns < 4; ++ns) {
#pragma unroll
        for (int reg = 0; reg < 4; ++reg) {
            int m = m0 + quad * 4 + reg;
            int n = n0 + ns * 16 + r;
            if constexpr (OF32) ((float*)C)[(size_t)m * N + n] = acc[ns][reg];
            else ((__hip_bfloat16*)C)[(size_t)m * N + n] = __float2bfloat16(acc[ns][reg]);
        }
    }
}

__global__ __launch_bounds__(256) void gemm_bt(const void* __restrict__ A, const void* __restrict__ W,
                                               void* __restrict__ C, int M, int N, int K,
                                               const int* __restrict__ flagp, int mode) {
    const int bf = *flagp;
    if (bf) {
        gemm_body<false, false, false>(A, W, C, M, N, K);
    } else if (mode == 0) {
        gemm_body<true, true, false>(A, W, C, M, N, K);
    } else {
        gemm_body<false, true, true>(A, W, C, M, N, K);
    }
}

// ---------------------------------------------------------------------------
// In-place RoPE + RMSNorm on bf16 rows. Row (bs,h) at base + bs*ld + h*D.
// ---------------------------------------------------------------------------
__global__ __launch_bounds__(256) void rope_rms(__hip_bfloat16* __restrict__ qk,
                                                const void* __restrict__ cosp,
                                                const void* __restrict__ sinp,
                                                int NH, int ld, const int* __restrict__ flagp) {
    const int bf = *flagp;
    const int wave = threadIdx.x >> 6;
    const int lane = threadIdx.x & 63;
    const int row = blockIdx.x * 4 + wave;   // row = bs*NH + h
    const int h = row % NH;
    const int bs = row / NH;
    const int s = bs % S_;

    __hip_bfloat16* p = qk + (size_t)bs * ld + h * D_;
    float x1 = __bfloat162float(p[lane]);
    float x2 = __bfloat162float(p[lane + 64]);
    float c, sn, eps;
    if (bf) {
        c   = __bfloat162float(((const __hip_bfloat16*)cosp)[s * 64 + lane]);
        sn  = __bfloat162float(((const __hip_bfloat16*)sinp)[s * 64 + lane]);
        eps = 0.0078125f;
    } else {
        c   = ((const float*)cosp)[s * 64 + lane];
        sn  = ((const float*)sinp)[s * 64 + lane];
        eps = 1.1920929e-07f;
    }
    float y1 = x1 * c + x2 * sn;
    float y2 = x2 * c - x1 * sn;
    float ss = y1 * y1 + y2 * y2;
#pragma unroll
    for (int m = 1; m < 64; m <<= 1) ss += __shfl_xor(ss, m, 64);
    float rinv = rsqrtf(ss * (1.0f / 128.0f) + eps);
    p[lane]      = __float2bfloat16(y1 * rinv);
    p[lane + 64] = __float2bfloat16(y2 * rinv);
}

// ---------------------------------------------------------------------------
// Flash attention v3 (MFMA, GQA-shared staging, reg-prefetch pipeline,
// pair-packed V/P LDS traffic).
// Block = 4 waves = the 4 q-heads of one (b,kvh) group; 32 q-rows/block.
//
// k-permutation (shared by P A-frag and V B-frag; MFMA invariant under a
// consistent k-perm): frag element k -> key = (k>>1) + 16*(k&1).
// Vt: u32 pair (V[key][d], V[key+16][d]); row d, pair `key` stored in group
//   g = (key>>2) ^ f(d), f(d) = ((d>>1)&3)^((d>>3)&3); slot = key&3.
// Pb: u32 pair (P[q][key=r], P[q][16+r]); row q, group = (r>>2)^(q>>2).
// Balanced dispatch: qt = x for b=1 else 63-x, so co-resident block pairs
// (id, id+256) sum to constant work.
// Pipeline: tile kt+1 global loads issue after barrier-2, consumed by
// ds_writes at the top of the next iteration (fine-grained vmcnt overlap).
// ---------------------------------------------------------------------------
#define KT_ 32
#define LDK 136

__global__ __launch_bounds__(256, 2) void attn_flash3(const __hip_bfloat16* __restrict__ Q,
                                                      const __hip_bfloat16* __restrict__ K,
                                                      const __hip_bfloat16* __restrict__ V,
                                                      __hip_bfloat16* __restrict__ O,
                                                      int ldq, int ldkv, int ldo) {
    __shared__ unsigned short Ks[KT_][LDK];        // 8704 B
    __shared__ unsigned int Vt[D_ * 16];           // 8192 B (pair-packed)
    __shared__ unsigned int Pb[4][2][16][16];      // 8192 B (pair-packed)

    const int tid = threadIdx.x;
    const int w = tid >> 6;
    const int lane = tid & 63;
    const int r = lane & 15;
    const int quad = lane >> 4;

    const int gy = blockIdx.y;                     // b*HKV + kvh
    const int kvh = gy % HKV_;
    const int b = gy / HKV_;
    // complementary work pairing across the two batches
    const int qt = b ? blockIdx.x : (gridDim.x - 1 - blockIdx.x);
    const int q0 = qt * 32;
    const int h = kvh * 4 + w;                     // this wave's q-head

    // Q fragments: 2 row-tiles x 4 k-chunks
    bf16x8 qf[2][4];
#pragma unroll
    for (int t = 0; t < 2; ++t) {
        const bf16_t* qp = (const bf16_t*)Q + (size_t)(b * S_ + q0 + t * 16 + r) * ldq + h * D_ + quad * 8;
#pragma unroll
        for (int c = 0; c < 4; ++c) qf[t][c] = *(const bf16x8*)(qp + c * 32);
    }

    f32x4 oacc[2][8] = {};
    f32x4 lacc[2] = {};
    float m_i[2][4];
#pragma unroll
    for (int t = 0; t < 2; ++t)
#pragma unroll
        for (int g = 0; g < 4; ++g) m_i[t][g] = -3e38f;

    const bf16_t* Kg = (const bf16_t*)K + (size_t)b * S_ * ldkv + kvh * D_;
    const bf16_t* Vg = (const bf16_t*)V + (size_t)b * S_ * ldkv + kvh * D_;

    bf16x8 ones;
#pragma unroll
    for (int j = 0; j < 8; ++j) ones[j] = (bf16_t)1.0f;

    const float SC2 = 0.08838834764831845f * 1.4426950408889634f;  // D^-0.5 * log2(e)

    // staging assignment: thread stages keys (skey, skey+16), dim chunk sdc
    const int skey = tid >> 4;                     // 0..15
    const int sdc = tid & 15;                      // 0..15
    union U4 { uint4 u; unsigned short s[8]; };
    U4 rk0, rk1, rv0, rv1;
    {
        const size_t o0 = (size_t)skey * ldkv + sdc * 8;
        const size_t o1 = o0 + (size_t)16 * ldkv;
        rk0.u = *(const uint4*)(Kg + o0);
        rk1.u = *(const uint4*)(Kg + o1);
        rv0.u = *(const uint4*)(Vg + o0);
        rv1.u = *(const uint4*)(Vg + o1);
    }

    for (int kt = 0; kt <= qt; ++kt) {
        const int k0 = kt * KT_;
        __syncthreads();
        // ---- write staged tile from regs ----
        *(uint4*)&Ks[skey][sdc * 8] = rk0.u;
        *(uint4*)&Ks[skey + 16][sdc * 8] = rk1.u;
#pragma unroll
        for (int j = 0; j < 8; ++j) {
            const int d = sdc * 8 + j;
            const int f = ((j >> 1) & 3) ^ (sdc & 3);      // ((d>>1)&3)^((d>>3)&3)
            const int grp = (skey >> 2) ^ f;
            Vt[d * 16 + grp * 4 + (skey & 3)] = (unsigned)rv0.s[j] | ((unsigned)rv1.s[j] << 16);
        }
        __syncthreads();
        // ---- prefetch next tile (overlaps with compute below) ----
        if (kt < qt) {
            const size_t o0 = (size_t)(k0 + KT_ + skey) * ldkv + sdc * 8;
            const size_t o1 = o0 + (size_t)16 * ldkv;
            rk0.u = *(const uint4*)(Kg + o0);
            rk1.u = *(const uint4*)(Kg + o1);
            rv0.u = *(const uint4*)(Vg + o0);
            rv1.u = *(const uint4*)(Vg + o1);
        }

        // ---- QK^T: S[2][16 x 32]; K-frags shared across row-tiles ----
        f32x4 s0[2] = {}, s1[2] = {};
#pragma unroll
        for (int c = 0; c < 4; ++c) {
            bf16x8 kb0 = *(const bf16x8*)&Ks[r][c * 32 + quad * 8];
            bf16x8 kb1 = *(const bf16x8*)&Ks[16 + r][c * 32 + quad * 8];
#pragma unroll
            for (int t = 0; t < 2; ++t) {
                s0[t] = __builtin_amdgcn_mfma_f32_16x16x32_bf16(qf[t][c], kb0, s0[t], 0, 0, 0);
                s1[t] = __builtin_amdgcn_mfma_f32_16x16x32_bf16(qf[t][c], kb1, s1[t], 0, 0, 0);
            }
        }

        const bool bnd = (kt == qt);
#pragma unroll
        for (int t = 0; t < 2; ++t) {
            float mt[4];
#pragma unroll
            for (int g = 0; g < 4; ++g) {
                s0[t][g] *= SC2;
                s1[t][g] *= SC2;
                if (bnd) {
                    const int qrow = q0 + t * 16 + quad * 4 + g;
                    if (k0 + r > qrow)      s0[t][g] = -1e38f;
                    if (k0 + 16 + r > qrow) s1[t][g] = -1e38f;
                }
                mt[g] = fmaxf(s0[t][g], s1[t][g]);
            }
#pragma unroll
            for (int msk = 1; msk < 16; msk <<= 1) {
#pragma unroll
                for (int g = 0; g < 4; ++g) mt[g] = fmaxf(mt[g], __shfl_xor(mt[g], msk, 64));
            }
            // ballot-gated rescale
            bool upd = false;
#pragma unroll
            for (int g = 0; g < 4; ++g) upd |= (mt[g] > m_i[t][g]);
            if (__ballot(upd)) {
#pragma unroll
                for (int g = 0; g < 4; ++g) {
                    const float mn = fmaxf(m_i[t][g], mt[g]);
                    const float al = exp2f(m_i[t][g] - mn);
                    m_i[t][g] = mn;
                    lacc[t][g] *= al;
#pragma unroll
                    for (int ns = 0; ns < 8; ++ns) oacc[t][ns][g] *= al;
                }
            }
            // p = 2^(s-m); pair-packed store (key r | key 16+r)
#pragma unroll
            for (int g = 0; g < 4; ++g) {
                const float p0 = exp2f(s0[t][g] - m_i[t][g]);
                const float p1 = exp2f(s1[t][g] - m_i[t][g]);
                const int row = quad * 4 + g;
                Pb[w][t][row][(((r >> 2) ^ quad) & 3) * 4 + (r & 3)] = packbf2(p0, p1);
            }
        }

        const int pgrp = ((quad ^ (r >> 2)) & 3) * 4;
        bf16x8 pf0 = *(const bf16x8*)&Pb[w][0][r][pgrp];
        bf16x8 pf1 = *(const bf16x8*)&Pb[w][1][r][pgrp];

        // row-sum l via ones-column MFMA (perm-invariant)
        lacc[0] = __builtin_amdgcn_mfma_f32_16x16x32_bf16(pf0, ones, lacc[0], 0, 0, 0);
        lacc[1] = __builtin_amdgcn_mfma_f32_16x16x32_bf16(pf1, ones, lacc[1], 0, 0, 0);

        // ---- PV: V-frags shared across row-tiles ----
#pragma unroll
        for (int ns = 0; ns < 8; ++ns) {
            const int d = ns * 16 + r;
            const int f = ((r >> 1) & 3) ^ ((2 * ns + (r >> 3)) & 3);  // ((d>>1)&3)^((d>>3)&3)
            bf16x8 vf = *(const bf16x8*)&Vt[d * 16 + ((quad ^ f) & 3) * 4];
            oacc[0][ns] = __builtin_amdgcn_mfma_f32_16x16x32_bf16(pf0, vf, oacc[0][ns], 0, 0, 0);
            oacc[1][ns] = __builtin_amdgcn_mfma_f32_16x16x32_bf16(pf1, vf, oacc[1][ns], 0, 0, 0);
        }
    }

    // ---- epilogue: O / l, store ----
#pragma unroll
    for (int t = 0; t < 2; ++t) {
#pragma unroll
        for (int g = 0; g < 4; ++g) {
            const float inv = 1.0f / lacc[t][g];
            const int qrow = q0 + t * 16 + quad * 4 + g;
            __hip_bfloat16* op = O + (size_t)(b * S_ + qrow) * ldo + h * D_;
#pragma unroll
            for (int ns = 0; ns < 8; ++ns)
                op[ns * 16 + r] = __float2bfloat16(oacc[t][ns][g] * inv);
        }
    }
}

// ---------------------------------------------------------------------------
extern "C" void kernel_launch(void* const* d_in, const int* in_sizes, int n_in,
                              void* d_out, int out_size, void* d_ws, size_t ws_size,
                              hipStream_t stream) {
    const void* x    = d_in[0];
    const void* cosp = d_in[1];
    const void* sinp = d_in[2];
    const void* Wq   = d_in[3];
    const void* Wk   = d_in[4];
    const void* Wv   = d_in[5];
    const void* Wo   = d_in[6];

    const int M = B_ * S_;                 // 4096
    const size_t MB = 1ull << 20;

    if (ws_size >= 28 * MB + 64) {
        // Fast path. ws: [0,16M)=xb then ao; [16M,28M)=Wqkv then Wo; flag at 28M.
        // d_out: qkv bf16 [4096,3072] (24 MB), then final output.
        char* ws = (char*)d_ws;
        bf16_t* xb = (bf16_t*)ws;
        bf16_t* wb = (bf16_t*)(ws + 16 * MB);
        bf16_t* wo = (bf16_t*)(ws + 16 * MB);
        bf16_t* ao = (bf16_t*)ws;
        int* flag  = (int*)(ws + 28 * MB);
        bf16_t* qkv = (bf16_t*)d_out;

        detect_dtype<<<1, 64, 0, stream>>>((const unsigned*)x, flag);

        // convert x, Wq, Wk, Wv -> bf16 (Wqkv contiguous [3072, 2048])
        Cseg sx{x,  xb,                          (B_ * S_ * HID_) / 8};
        Cseg sq{Wq, wb,                          (H_ * D_ * HID_) / 8};
        Cseg sk{Wk, wb + (size_t)2048 * HID_,    (HKV_ * D_ * HID_) / 8};
        Cseg sv{Wv, wb + (size_t)2560 * HID_,    (HKV_ * D_ * HID_) / 8};
        convert_bf16<<<dim3(4096, 4), 256, 0, stream>>>(sx, sq, sk, sv, flag);

        // Fused QKV projection: [4096,2048] x [3072,2048]^T -> qkv [4096,3072]
        gemm_lds<<<dim3(3072 / 128, M / 128), 256, 0, stream>>>(xb, wb, qkv, M, 3072, HID_, flag, 0);

        // convert Wo -> bf16 (wb dead; wo overlays wb)
        Cseg so{Wo, wo, (HID_ * H_ * D_) / 8};
        convert_bf16<<<dim3(2048, 1), 256, 0, stream>>>(so, so, so, so, flag);

        // RoPE + RMSNorm in-place: q cols [0,2048), k cols [2048,2560)
        rope_rms<<<(B_ * S_ * H_) / 4, 256, 0, stream>>>((__hip_bfloat16*)qkv, cosp, sinp, H_, 3072, flag);
        rope_rms<<<(B_ * S_ * HKV_) / 4, 256, 0, stream>>>((__hip_bfloat16*)(qkv + 2048), cosp, sinp, HKV_, 3072, flag);

        // Flash attention v3: Q/K/V strided in qkv; O -> ao (xb dead)
        attn_flash3<<<dim3(S_ / 32, B_ * HKV_), 256, 0, stream>>>(
            (const __hip_bfloat16*)qkv, (const __hip_bfloat16*)(qkv + 2048),
            (const __hip_bfloat16*)(qkv + 2560), (__hip_bfloat16*)ao, 3072, 3072, 2048);

        // Output projection: ao x Wo^T -> d_out (fp32 if flag=0)
        gemm_lds<<<dim3(HID_ / 128, M / 128), 256, 0, stream>>>(ao, wo, d_out, M, HID_, H_ * D_, flag, 1);
    } else {
        // Fallback: proven path (ws >= 16 MB + 4).
        __hip_bfloat16* qb = (__hip_bfloat16*)d_ws;
        int* flag = (int*)((char*)d_ws + (size_t)M * (H_ * D_) * sizeof(__hip_bfloat16));
        __hip_bfloat16* kb = (__hip_bfloat16*)d_out;
        __hip_bfloat16* vb = kb + (size_t)M * (HKV_ * D_);

        detect_dtype<<<1, 64, 0, stream>>>((const unsigned*)x, flag);

        gemm_bt<<<dim3((H_ * D_) / 64, M / 64), 256, 0, stream>>>(x, Wq, qb, M, H_ * D_, HID_, flag, 0);
        gemm_bt<<<dim3((HKV_ * D_) / 64, M / 64), 256, 0, stream>>>(x, Wk, kb, M, HKV_ * D_, HID_, flag, 0);
        gemm_bt<<<dim3((HKV_ * D_) / 64, M / 64), 256, 0, stream>>>(x, Wv, vb, M, HKV_ * D_, HID_, flag, 0);

        rope_rms<<<(B_ * S_ * H_) / 4, 256, 0, stream>>>(qb, cosp, sinp, H_, H_ * D_, flag);
        rope_rms<<<(B_ * S_ * HKV_) / 4, 256, 0, stream>>>(kb, cosp, sinp, HKV_, HKV_ * D_, flag);

        attn_flash3<<<dim3(S_ / 32, B_ * HKV_), 256, 0, stream>>>(qb, kb, vb, qb, H_ * D_, HKV_ * D_, H_ * D_);

        gemm_bt<<<dim3(HID_ / 64, M / 64), 256, 0, stream>>>(qb, Wo, d_out, M, HID_, H_ * D_, flag, 1);
    }
}